// Round 17
// baseline (1870.558 us; speedup 1.0000x reference)
//
#include <hip/hip_runtime.h>

#define N_NODES 50000
#define N_EDGES 800000
#define N_GRAPHS 512
#define IN_DIM 256
#define HID 512
#define BN_EPS 1e-5f

typedef __attribute__((ext_vector_type(8))) short bf16x8;
typedef __attribute__((ext_vector_type(4))) float f32x4;

__device__ inline void split_bf16(float a, unsigned short& hi, unsigned short& lo) {
  unsigned u = __float_as_uint(a);
  hi = (unsigned short)(u >> 16);
  float fh = __uint_as_float(u & 0xFFFF0000u);
  float r = a - fh;
  lo = (unsigned short)(__float_as_uint(r) >> 16);
}

__device__ inline void split4_store(float4 v, unsigned short* hip, unsigned short* lop) {
  unsigned short h0, h1, h2, h3, l0, l1, l2, l3;
  split_bf16(v.x, h0, l0);
  split_bf16(v.y, h1, l1);
  split_bf16(v.z, h2, l2);
  split_bf16(v.w, h3, l3);
  uint2 hv, lv;
  hv.x = (unsigned)h0 | ((unsigned)h1 << 16);
  hv.y = (unsigned)h2 | ((unsigned)h3 << 16);
  lv.x = (unsigned)l0 | ((unsigned)l1 << 16);
  lv.y = (unsigned)l2 | ((unsigned)l3 << 16);
  *(uint2*)hip = hv;
  *(uint2*)lop = lv;
}

__device__ inline float4 bnrelu4(float4 v, float4 s, float4 h) {
  float4 o;
  o.x = fmaxf(fmaf(v.x, s.x, h.x), 0.f);
  o.y = fmaxf(fmaf(v.y, s.y, h.y), 0.f);
  o.z = fmaxf(fmaf(v.z, s.z, h.z), 0.f);
  o.w = fmaxf(fmaf(v.w, s.w, h.w), 0.f);
  return o;
}

// ------------------------------------------------- CSR build
__global__ __launch_bounds__(256) void hist_dst(const int* __restrict__ dst,
                                                int* __restrict__ deg) {
  for (int e = blockIdx.x * 256 + threadIdx.x; e < N_EDGES; e += gridDim.x * 256)
    atomicAdd(&deg[dst[e]], 1);
}

__global__ __launch_bounds__(1024) void scan_deg(const int* __restrict__ deg,
                                                 int* __restrict__ off,
                                                 int* __restrict__ cursor) {
  __shared__ int partial[1024];
  const int t = threadIdx.x;
  const int CHUNK = 49;
  const int base = t * CHUNK;
  int mysum = 0;
  for (int i = 0; i < CHUNK; ++i) {
    int idx = base + i;
    if (idx < N_NODES) mysum += deg[idx];
  }
  partial[t] = mysum;
  __syncthreads();
  for (int st = 1; st < 1024; st <<= 1) {
    int v = (t >= st) ? partial[t - st] : 0;
    __syncthreads();
    partial[t] += v;
    __syncthreads();
  }
  int run = partial[t] - mysum;
  for (int i = 0; i < CHUNK; ++i) {
    int idx = base + i;
    if (idx < N_NODES) {
      off[idx] = run;
      cursor[idx] = run;
      run += deg[idx];
    }
  }
  if (t == 1023) off[N_NODES] = N_EDGES;
}

__global__ __launch_bounds__(256) void fill_csr(const int* __restrict__ src,
                                                const int* __restrict__ dst,
                                                int* __restrict__ cursor,
                                                int* __restrict__ eidx) {
  for (int e = blockIdx.x * 256 + threadIdx.x; e < N_EDGES; e += gridDim.x * 256) {
    int p = atomicAdd(&cursor[dst[e]], 1);
    eidx[p] = src[e];
  }
}

// ------------------------------------------------- gather-aggregate -> node-block packed output
// Full-row version (layer 0, D=256).
template <int ROWF4, int HASBN>
__global__ __launch_bounds__(256) void agg_pk(const float4* __restrict__ h4,
                                              const int* __restrict__ off,
                                              const int* __restrict__ eidx,
                                              const float4* __restrict__ scale4,
                                              const float4* __restrict__ shift4,
                                              unsigned short* __restrict__ zp) {
  const int n = blockIdx.x * 4 + (threadIdx.x >> 6);
  if (n >= N_NODES) return;
  const int lane = threadIdx.x & 63;
  const int ROW = ROWF4 * 64;
  float4 sc[ROWF4], sh[ROWF4];
  if (HASBN) {
#pragma unroll
    for (int j = 0; j < ROWF4; ++j) {
      sc[j] = scale4[j * 64 + lane];
      sh[j] = shift4[j * 64 + lane];
    }
  }
  float4 v[ROWF4];
  const float4* hn = h4 + (long long)n * ROW;
#pragma unroll
  for (int j = 0; j < ROWF4; ++j) {
    float4 a = hn[j * 64 + lane];
    v[j] = HASBN ? bnrelu4(a, sc[j], sh[j]) : a;
  }

  int p = off[n];
  const int pe = off[n + 1];
  for (; p < pe; p += 8) {
    const float4* hp[8];
    float m[8];
#pragma unroll
    for (int e = 0; e < 8; ++e) {
      bool ok = (p + e) < pe;
      int idx = ok ? (p + e) : (pe - 1);
      hp[e] = h4 + (long long)eidx[idx] * ROW;
      m[e] = ok ? 1.f : 0.f;
    }
#pragma unroll
    for (int j = 0; j < ROWF4; ++j) {
      float4 t[8];
#pragma unroll
      for (int e = 0; e < 8; ++e) {
        t[e] = hp[e][j * 64 + lane];
        if (HASBN) t[e] = bnrelu4(t[e], sc[j], sh[j]);
      }
#pragma unroll
      for (int e = 0; e < 8; ++e) {
        v[j].x = fmaf(t[e].x, m[e], v[j].x);
        v[j].y = fmaf(t[e].y, m[e], v[j].y);
        v[j].z = fmaf(t[e].z, m[e], v[j].z);
        v[j].w = fmaf(t[e].w, m[e], v[j].w);
      }
    }
  }
  const int nd = n & 63, tile = n >> 6;
#pragma unroll
  for (int j = 0; j < ROWF4; ++j) {
    int cj = j * 64 + lane;
    int ks = cj >> 3, k4 = cj & 7;
    size_t base = ((size_t)tile * (ROWF4 * 8) + ks) * 4096 + (size_t)nd * 32 +
                  (size_t)k4 * 4;
    split4_store(v[j], zp + base, zp + base + 2048);
  }
}

// ------------------------------------------------- channel-half gather-aggregate (D=512)
template <int HASBN>
__global__ __launch_bounds__(256) void agg_pk_half(const float4* __restrict__ h4,
                                                   const int* __restrict__ off,
                                                   const int* __restrict__ eidx,
                                                   const float4* __restrict__ scale4,
                                                   const float4* __restrict__ shift4,
                                                   unsigned short* __restrict__ zp,
                                                   int jsel) {
  const int n = blockIdx.x * 4 + (threadIdx.x >> 6);
  if (n >= N_NODES) return;
  const int lane = threadIdx.x & 63;
  const int ROW = 128;
  const int cj = jsel * 64 + lane;
  float4 sc, sh;
  if (HASBN) {
    sc = scale4[cj];
    sh = shift4[cj];
  }
  const float4* hn = h4 + (long long)n * ROW;
  float4 a0 = hn[cj];
  float4 v = HASBN ? bnrelu4(a0, sc, sh) : a0;

  int p = off[n];
  const int pe = off[n + 1];
  for (; p < pe; p += 8) {
    const float4* hp[8];
    float m[8];
#pragma unroll
    for (int e = 0; e < 8; ++e) {
      bool ok = (p + e) < pe;
      int idx = ok ? (p + e) : (pe - 1);
      hp[e] = h4 + (long long)eidx[idx] * ROW;
      m[e] = ok ? 1.f : 0.f;
    }
    float4 t[8];
#pragma unroll
    for (int e = 0; e < 8; ++e) {
      t[e] = hp[e][cj];
      if (HASBN) t[e] = bnrelu4(t[e], sc, sh);
    }
#pragma unroll
    for (int e = 0; e < 8; ++e) {
      v.x = fmaf(t[e].x, m[e], v.x);
      v.y = fmaf(t[e].y, m[e], v.y);
      v.z = fmaf(t[e].z, m[e], v.z);
      v.w = fmaf(t[e].w, m[e], v.w);
    }
  }
  const int nd = n & 63, tile = n >> 6;
  const int ks = cj >> 3, k4 = cj & 7;
  size_t base = ((size_t)tile * 16 + ks) * 4096 + (size_t)nd * 32 + (size_t)k4 * 4;
  split4_store(v, zp + base, zp + base + 2048);
}

// ------------------------------------------------- W pre-pack
__global__ __launch_bounds__(256) void wt_build(const float* __restrict__ W, // [K][512]
                                                unsigned short* __restrict__ Wp,
                                                int KS) {
  int gid = blockIdx.x * 256 + threadIdx.x;
  int total = 2 * KS * 8192;
  if (gid >= total) return;
  int blk = gid >> 13;
  int rem = gid & 8191;
  int cf = rem >> 9;
  int q = (rem >> 7) & 3;
  int c = (rem >> 3) & 15;
  int j = rem & 7;
  int bx = blk / KS, ks = blk - bx * KS;
  int chan = bx * 256 + cf * 16 + c;
  int k = ks * 32 + q * 8 + j;
  float v = W[(size_t)k * 512 + chan];
  unsigned short h, l;
  split_bf16(v, h, l);
  Wp[(size_t)blk * 16384 + rem] = h;
  Wp[(size_t)blk * 16384 + 8192 + rem] = l;
}

// ------------------------------------------------- 2-tile register-shared-W split-bf16 MFMA GEMM.
// Each block: (bx chan-half, tile pair). Per K-step: load W frags ONCE (8x16B) + A for two
// tiles (16x16B) as one 24-load batch (needs ~240 VGPR -> launch_bounds(256,1)), then 96 MFMA.
// 2x better load:MFMA ratio than 1-tile; no LDS, no barriers.
template <int KS, int STATS, int PACKOUT>
__global__ __launch_bounds__(256, 1) void gemm_pk(const unsigned short* __restrict__ Ap,
                                                  const unsigned short* __restrict__ Wp,
                                                  const float* __restrict__ bias,
                                                  float* __restrict__ Cf,
                                                  unsigned short* __restrict__ Cp,
                                                  float* __restrict__ stat_sum,
                                                  float* __restrict__ stat_sq,
                                                  int N, int NTtiles, int relu) {
  const int bx = blockIdx.x;
  const int t0 = blockIdx.y * 2;
  const int t1r = t0 + 1;
  const bool has1 = t1r < NTtiles;
  const int t1 = has1 ? t1r : t0;
  const int tid = threadIdx.x;
  const int wv = tid >> 6, ln = tid & 63;
  const int q = ln >> 4, ccs = ln & 15;

  f32x4 acc0[4][4], acc1[4][4];
#pragma unroll
  for (int i = 0; i < 4; ++i)
#pragma unroll
    for (int j = 0; j < 4; ++j) {
      acc0[i][j] = f32x4{0.f, 0.f, 0.f, 0.f};
      acc1[i][j] = f32x4{0.f, 0.f, 0.f, 0.f};
    }

  const unsigned short* wp =
      Wp + ((size_t)bx * KS) * 16384 + (size_t)(wv * 4) * 512 + (size_t)ln * 8;
  const unsigned short* ap0 =
      Ap + (size_t)t0 * KS * 4096 + (size_t)ccs * 32 + (size_t)q * 8;
  const unsigned short* ap1 =
      Ap + (size_t)t1 * KS * 4096 + (size_t)ccs * 32 + (size_t)q * 8;

  for (int ks = 0; ks < KS; ++ks) {
    const unsigned short* w = wp + (size_t)ks * 16384;
    const unsigned short* a0 = ap0 + (size_t)ks * 4096;
    const unsigned short* a1 = ap1 + (size_t)ks * 4096;
    bf16x8 wh[4], wl[4], a0h[4], a0l[4], a1h[4], a1l[4];
#pragma unroll
    for (int i = 0; i < 4; ++i) {
      wh[i] = *(const bf16x8*)(w + i * 512);
      wl[i] = *(const bf16x8*)(w + 8192 + i * 512);
      a0h[i] = *(const bf16x8*)(a0 + i * 512);
      a0l[i] = *(const bf16x8*)(a0 + 2048 + i * 512);
      a1h[i] = *(const bf16x8*)(a1 + i * 512);
      a1l[i] = *(const bf16x8*)(a1 + 2048 + i * 512);
    }
#pragma unroll
    for (int i = 0; i < 4; ++i)
#pragma unroll
      for (int j = 0; j < 4; ++j) {
        acc0[i][j] = __builtin_amdgcn_mfma_f32_16x16x32_bf16(wh[i], a0h[j], acc0[i][j], 0, 0, 0);
        acc0[i][j] = __builtin_amdgcn_mfma_f32_16x16x32_bf16(wh[i], a0l[j], acc0[i][j], 0, 0, 0);
        acc0[i][j] = __builtin_amdgcn_mfma_f32_16x16x32_bf16(wl[i], a0h[j], acc0[i][j], 0, 0, 0);
        acc1[i][j] = __builtin_amdgcn_mfma_f32_16x16x32_bf16(wh[i], a1h[j], acc1[i][j], 0, 0, 0);
        acc1[i][j] = __builtin_amdgcn_mfma_f32_16x16x32_bf16(wh[i], a1l[j], acc1[i][j], 0, 0, 0);
        acc1[i][j] = __builtin_amdgcn_mfma_f32_16x16x32_bf16(wl[i], a1h[j], acc1[i][j], 0, 0, 0);
      }
  }

  // epilogue per tile: acc row = chan ((ln>>4)*4+reg), col = node (ln&15)
  const int chanb = bx * 256 + wv * 64 + (ln >> 4) * 4;
  float4 s4[4], q4[4];
  if (STATS) {
#pragma unroll
    for (int i = 0; i < 4; ++i) {
      s4[i] = make_float4(0.f, 0.f, 0.f, 0.f);
      q4[i] = make_float4(0.f, 0.f, 0.f, 0.f);
    }
  }

#define EPILOGUE(ACC, TILE, ACTIVE)                                              \
  {                                                                              \
    const int n0_ = (TILE)*64;                                                   \
    _Pragma("unroll") for (int j = 0; j < 4; ++j) {                              \
      int node = n0_ + j * 16 + (ln & 15);                                       \
      bool valid = (ACTIVE) && node < N;                                         \
      int nd = node & 63;                                                        \
      int tile2 = node >> 6;                                                     \
      _Pragma("unroll") for (int i = 0; i < 4; ++i) {                            \
        int chan = chanb + i * 16;                                               \
        float4 bv = *(const float4*)(bias + chan);                               \
        f32x4 a = ACC[i][j];                                                     \
        float4 o;                                                                \
        o.x = a[0] + bv.x;                                                       \
        o.y = a[1] + bv.y;                                                       \
        o.z = a[2] + bv.z;                                                       \
        o.w = a[3] + bv.w;                                                       \
        if (relu) {                                                              \
          o.x = fmaxf(o.x, 0.f);                                                 \
          o.y = fmaxf(o.y, 0.f);                                                 \
          o.z = fmaxf(o.z, 0.f);                                                 \
          o.w = fmaxf(o.w, 0.f);                                                 \
        }                                                                        \
        if (PACKOUT) {                                                           \
          if (valid) {                                                           \
            size_t base = ((size_t)tile2 * 16 + (size_t)(chan >> 5)) * 4096 +    \
                          (size_t)nd * 32 + (size_t)(chan & 31);                 \
            split4_store(o, Cp + base, Cp + base + 2048);                        \
          }                                                                      \
        } else {                                                                 \
          if (valid) *(float4*)(Cf + (size_t)node * 512 + chan) = o;             \
          if (STATS) {                                                           \
            if (!valid) o = make_float4(0.f, 0.f, 0.f, 0.f);                     \
            s4[i].x += o.x; s4[i].y += o.y; s4[i].z += o.z; s4[i].w += o.w;      \
            q4[i].x += o.x * o.x; q4[i].y += o.y * o.y;                          \
            q4[i].z += o.z * o.z; q4[i].w += o.w * o.w;                          \
          }                                                                      \
        }                                                                        \
      }                                                                          \
    }                                                                            \
  }

  EPILOGUE(acc0, t0, true)
  EPILOGUE(acc1, t1r, has1)
#undef EPILOGUE

  if (STATS) {
#pragma unroll
    for (int i = 0; i < 4; ++i) {
#pragma unroll
      for (int mask = 1; mask < 16; mask <<= 1) {
        s4[i].x += __shfl_xor(s4[i].x, mask);
        s4[i].y += __shfl_xor(s4[i].y, mask);
        s4[i].z += __shfl_xor(s4[i].z, mask);
        s4[i].w += __shfl_xor(s4[i].w, mask);
        q4[i].x += __shfl_xor(q4[i].x, mask);
        q4[i].y += __shfl_xor(q4[i].y, mask);
        q4[i].z += __shfl_xor(q4[i].z, mask);
        q4[i].w += __shfl_xor(q4[i].w, mask);
      }
    }
    if ((ln & 15) == 0) {
#pragma unroll
      for (int i = 0; i < 4; ++i) {
        int chan = chanb + i * 16;
        atomicAdd(&stat_sum[chan + 0], s4[i].x);
        atomicAdd(&stat_sum[chan + 1], s4[i].y);
        atomicAdd(&stat_sum[chan + 2], s4[i].z);
        atomicAdd(&stat_sum[chan + 3], s4[i].w);
        atomicAdd(&stat_sq[chan + 0], q4[i].x);
        atomicAdd(&stat_sq[chan + 1], q4[i].y);
        atomicAdd(&stat_sq[chan + 2], q4[i].z);
        atomicAdd(&stat_sq[chan + 3], q4[i].w);
      }
    }
  }
}

// ------------------------------------------------- BN finalize
__global__ __launch_bounds__(512) void bn_finalize(const float* __restrict__ sum,
                                                   const float* __restrict__ sumsq,
                                                   const float* __restrict__ g,
                                                   const float* __restrict__ b,
                                                   float* __restrict__ scale,
                                                   float* __restrict__ shift) {
  const int c = threadIdx.x;
  const float invN = 1.0f / (float)N_NODES;
  float mu = sum[c] * invN;
  float var = sumsq[c] * invN - mu * mu;
  float sc = rsqrtf(var + BN_EPS) * g[c];
  scale[c] = sc;
  shift[c] = fmaf(-mu, sc, b[c]);
}

// ------------------------------------------------- pool bounds
__global__ __launch_bounds__(512) void pool_bounds(const int* __restrict__ batch,
                                                   int* __restrict__ gstart) {
  const int g = threadIdx.x;
  int lo = 0, hi = N_NODES;
  while (lo < hi) {
    int mid = (lo + hi) >> 1;
    if (batch[mid] < g) lo = mid + 1;
    else hi = mid;
  }
  gstart[g] = lo;
  if (g == 0) gstart[N_GRAPHS] = N_NODES;
}

// ------------------------------------------------- segmented add pool + fused BN -> node-block pack
__global__ __launch_bounds__(128) void gpool_bn(const float4* __restrict__ z4,
                                                const int* __restrict__ gstart,
                                                const float4* __restrict__ scale4,
                                                const float4* __restrict__ shift4,
                                                unsigned short* __restrict__ gpp) {
  const int g = blockIdx.x;
  const int t = threadIdx.x;
  const int s = gstart[g], e = gstart[g + 1];
  const float4 sc = scale4[t], sh = shift4[t];
  float4 acc = make_float4(0.f, 0.f, 0.f, 0.f);
  for (int n = s; n < e; ++n) {
    float4 v = bnrelu4(z4[(size_t)n * 128 + t], sc, sh);
    acc.x += v.x;
    acc.y += v.y;
    acc.z += v.z;
    acc.w += v.w;
  }
  const int tile = g >> 6, nd = g & 63;
  const int ks = t >> 3, k4 = t & 7;
  size_t base = ((size_t)tile * 16 + ks) * 4096 + (size_t)nd * 32 + (size_t)k4 * 4;
  split4_store(acc, gpp + base, gpp + base + 2048);
}

// ------------------------------------------------- classifier tail
__global__ __launch_bounds__(64) void clf2_softmax(const float* __restrict__ hidden,
                                                   const float* __restrict__ w2,
                                                   const float* __restrict__ b2,
                                                   float* __restrict__ out) {
  const int g = blockIdx.x;
  const int lane = threadIdx.x;
  float acc[10];
#pragma unroll
  for (int j = 0; j < 10; ++j) acc[j] = 0.f;
  for (int k = lane; k < HID; k += 64) {
    float hv = hidden[(long long)g * HID + k];
#pragma unroll
    for (int j = 0; j < 10; ++j) acc[j] += hv * w2[k * 10 + j];
  }
#pragma unroll
  for (int j = 0; j < 10; ++j) {
    for (int o = 32; o > 0; o >>= 1) acc[j] += __shfl_down(acc[j], o);
  }
  if (lane == 0) {
    float lg[10], pb[10];
    float mx = -1e30f;
#pragma unroll
    for (int j = 0; j < 10; ++j) {
      lg[j] = acc[j] + b2[j];
      mx = fmaxf(mx, lg[j]);
    }
    float se = 0.f;
#pragma unroll
    for (int j = 0; j < 10; ++j) {
      pb[j] = __expf(lg[j] - mx);
      se += pb[j];
    }
    float inv = 1.f / se;
    int am = 0;
    float best = lg[0];
#pragma unroll
    for (int j = 1; j < 10; ++j) {
      if (lg[j] > best) { best = lg[j]; am = j; }
    }
#pragma unroll
    for (int j = 0; j < 10; ++j) out[g * 10 + j] = lg[j];
#pragma unroll
    for (int j = 0; j < 10; ++j) out[N_GRAPHS * 10 + g * 10 + j] = pb[j] * inv;
    out[2 * N_GRAPHS * 10 + g] = (float)am;
#pragma unroll
    for (int j = 0; j < 10; ++j)
      out[2 * N_GRAPHS * 10 + N_GRAPHS + g * 10 + j] = (j == am) ? 1.f : 0.f;
  }
}

// ----------------------------------------------------------------- launch
extern "C" void kernel_launch(void* const* d_in, const int* in_sizes, int n_in,
                              void* d_out, int out_size, void* d_ws, size_t ws_size,
                              hipStream_t stream) {
  const float* x = (const float*)d_in[0];
  const int* src = (const int*)d_in[1];
  const int* dstE = src + N_EDGES;
  const int* batch = (const int*)d_in[2];
  const float* w0a = (const float*)d_in[3];
  const float* b0a = (const float*)d_in[4];
  const float* w0b = (const float*)d_in[5];
  const float* b0b = (const float*)d_in[6];
  const float* w1a = (const float*)d_in[7];
  const float* b1a = (const float*)d_in[8];
  const float* w1b = (const float*)d_in[9];
  const float* b1b = (const float*)d_in[10];
  const float* w2a = (const float*)d_in[11];
  const float* b2a = (const float*)d_in[12];
  const float* w2b = (const float*)d_in[13];
  const float* b2b = (const float*)d_in[14];
  const float* bng[3] = {(const float*)d_in[15], (const float*)d_in[17], (const float*)d_in[19]};
  const float* bnb[3] = {(const float*)d_in[16], (const float*)d_in[18], (const float*)d_in[20]};
  const float* clf_w1 = (const float*)d_in[21];
  const float* clf_b1 = (const float*)d_in[22];
  const float* clf_w2 = (const float*)d_in[23];
  const float* clf_b2 = (const float*)d_in[24];
  float* out = (float*)d_out;

  // ---- workspace layout (~218 MB)
  const long long BUF = 25624576LL;
  float* bufA = (float*)d_ws;
  float* bufB = bufA + BUF;
  float* bnsum = bufB + BUF;
  float* bnsq = bnsum + 512;
  float* scale = bnsq + 512;
  float* shift = scale + 512;
  unsigned short* gpPack = (unsigned short*)(shift + 512);
  float* hidden = (float*)(gpPack + 524288);
  unsigned short* wp0a = (unsigned short*)(hidden + 262144);
  unsigned short* wp0b = wp0a + 262144;
  unsigned short* wp1a = wp0b + 524288;
  unsigned short* wp1b = wp1a + 524288;
  unsigned short* wp2a = wp1b + 524288;
  unsigned short* wp2b = wp2a + 524288;
  unsigned short* wpc1 = wp2b + 524288;
  int* deg = (int*)(wpc1 + 524288);
  int* off = deg + N_NODES;
  int* cursor = off + N_NODES + 1;
  int* eidx = cursor + N_NODES;
  int* gstart = eidx + N_EDGES;

  // ---- build CSR + pool bounds
  hipMemsetAsync(deg, 0, N_NODES * sizeof(int), stream);
  hipLaunchKernelGGL(hist_dst, dim3(3125), dim3(256), 0, stream, dstE, deg);
  hipLaunchKernelGGL(scan_deg, dim3(1), dim3(1024), 0, stream, deg, off, cursor);
  hipLaunchKernelGGL(fill_csr, dim3(3125), dim3(256), 0, stream, src, dstE, cursor, eidx);
  hipLaunchKernelGGL(pool_bounds, dim3(1), dim3(512), 0, stream, batch, gstart);

  // ---- pre-pack weights
  hipLaunchKernelGGL(wt_build, dim3(512), dim3(256), 0, stream, w0a, wp0a, 8);
  hipLaunchKernelGGL(wt_build, dim3(1024), dim3(256), 0, stream, w0b, wp0b, 16);
  hipLaunchKernelGGL(wt_build, dim3(1024), dim3(256), 0, stream, w1a, wp1a, 16);
  hipLaunchKernelGGL(wt_build, dim3(1024), dim3(256), 0, stream, w1b, wp1b, 16);
  hipLaunchKernelGGL(wt_build, dim3(1024), dim3(256), 0, stream, w2a, wp2a, 16);
  hipLaunchKernelGGL(wt_build, dim3(1024), dim3(256), 0, stream, w2b, wp2b, 16);
  hipLaunchKernelGGL(wt_build, dim3(1024), dim3(256), 0, stream, clf_w1, wpc1, 16);

  const unsigned short* wpa[3] = {wp0a, wp1a, wp2a};
  const unsigned short* wpb[3] = {wp0b, wp1b, wp2b};
  const float* ba[3] = {b0a, b1a, b2a};
  const float* bb[3] = {b0b, b1b, b2b};

  const int NT = (N_NODES + 63) / 64;            // 782
  const int NTP = (NT + 1) / 2;                  // 391 tile pairs
  const int nagg = (N_NODES + 3) / 4;

  float* P = bufA;
  float* Q = bufB;
  for (int layer = 0; layer < 3; ++layer) {
    if (layer == 0) {
      hipLaunchKernelGGL((agg_pk<1, 0>), dim3(nagg), dim3(256), 0, stream,
                         (const float4*)x, off, eidx, nullptr, nullptr,
                         (unsigned short*)Q);
    } else {
      hipLaunchKernelGGL((agg_pk_half<1>), dim3(nagg), dim3(256), 0, stream,
                         (const float4*)P, off, eidx, (const float4*)scale,
                         (const float4*)shift, (unsigned short*)Q, 0);
      hipLaunchKernelGGL((agg_pk_half<1>), dim3(nagg), dim3(256), 0, stream,
                         (const float4*)P, off, eidx, (const float4*)scale,
                         (const float4*)shift, (unsigned short*)Q, 1);
    }
    { float* t = P; P = Q; Q = t; }
    if (layer == 0) {
      hipLaunchKernelGGL((gemm_pk<8, 0, 1>), dim3(2, NTP), dim3(256), 0, stream,
                         (const unsigned short*)P, wpa[layer], ba[layer],
                         (float*)nullptr, (unsigned short*)Q, nullptr, nullptr,
                         N_NODES, NT, 1);
    } else {
      hipLaunchKernelGGL((gemm_pk<16, 0, 1>), dim3(2, NTP), dim3(256), 0, stream,
                         (const unsigned short*)P, wpa[layer], ba[layer],
                         (float*)nullptr, (unsigned short*)Q, nullptr, nullptr,
                         N_NODES, NT, 1);
    }
    { float* t = P; P = Q; Q = t; }
    hipMemsetAsync(bnsum, 0, 2 * 512 * sizeof(float), stream);
    hipLaunchKernelGGL((gemm_pk<16, 1, 0>), dim3(2, NTP), dim3(256), 0, stream,
                       (const unsigned short*)P, wpb[layer], bb[layer],
                       Q, (unsigned short*)nullptr, bnsum, bnsq,
                       N_NODES, NT, 0);
    { float* t = P; P = Q; Q = t; }
    hipLaunchKernelGGL(bn_finalize, dim3(1), dim3(512), 0, stream,
                       bnsum, bnsq, bng[layer], bnb[layer], scale, shift);
  }

  hipLaunchKernelGGL(gpool_bn, dim3(N_GRAPHS), dim3(128), 0, stream,
                     (const float4*)P, gstart, (const float4*)scale,
                     (const float4*)shift, gpPack);
  hipLaunchKernelGGL((gemm_pk<16, 0, 0>), dim3(2, 4), dim3(256), 0, stream,
                     (const unsigned short*)gpPack, wpc1, clf_b1,
                     hidden, (unsigned short*)nullptr, nullptr, nullptr,
                     N_GRAPHS, 8, 1);
  hipLaunchKernelGGL(clf2_softmax, dim3(N_GRAPHS), dim3(64), 0, stream,
                     hidden, clf_w2, clf_b2, out);
}

// Round 18
// 1620.048 us; speedup vs baseline: 1.1546x; 1.1546x over previous
//
#include <hip/hip_runtime.h>

#define N_NODES 50000
#define N_EDGES 800000
#define N_GRAPHS 512
#define IN_DIM 256
#define HID 512
#define BN_EPS 1e-5f

typedef __attribute__((ext_vector_type(8))) short bf16x8;
typedef __attribute__((ext_vector_type(4))) float f32x4;

__device__ inline void split_bf16(float a, unsigned short& hi, unsigned short& lo) {
  unsigned u = __float_as_uint(a);
  hi = (unsigned short)(u >> 16);
  float fh = __uint_as_float(u & 0xFFFF0000u);
  float r = a - fh;
  lo = (unsigned short)(__float_as_uint(r) >> 16);
}

__device__ inline void split4_store(float4 v, unsigned short* hip, unsigned short* lop) {
  unsigned short h0, h1, h2, h3, l0, l1, l2, l3;
  split_bf16(v.x, h0, l0);
  split_bf16(v.y, h1, l1);
  split_bf16(v.z, h2, l2);
  split_bf16(v.w, h3, l3);
  uint2 hv, lv;
  hv.x = (unsigned)h0 | ((unsigned)h1 << 16);
  hv.y = (unsigned)h2 | ((unsigned)h3 << 16);
  lv.x = (unsigned)l0 | ((unsigned)l1 << 16);
  lv.y = (unsigned)l2 | ((unsigned)l3 << 16);
  *(uint2*)hip = hv;
  *(uint2*)lop = lv;
}

__device__ inline float4 bnrelu4(float4 v, float4 s, float4 h) {
  float4 o;
  o.x = fmaxf(fmaf(v.x, s.x, h.x), 0.f);
  o.y = fmaxf(fmaf(v.y, s.y, h.y), 0.f);
  o.z = fmaxf(fmaf(v.z, s.z, h.z), 0.f);
  o.w = fmaxf(fmaf(v.w, s.w, h.w), 0.f);
  return o;
}

// ------------------------------------------------- CSR build
__global__ __launch_bounds__(256) void hist_dst(const int* __restrict__ dst,
                                                int* __restrict__ deg) {
  for (int e = blockIdx.x * 256 + threadIdx.x; e < N_EDGES; e += gridDim.x * 256)
    atomicAdd(&deg[dst[e]], 1);
}

__global__ __launch_bounds__(1024) void scan_deg(const int* __restrict__ deg,
                                                 int* __restrict__ off,
                                                 int* __restrict__ cursor) {
  __shared__ int partial[1024];
  const int t = threadIdx.x;
  const int CHUNK = 49;
  const int base = t * CHUNK;
  int mysum = 0;
  for (int i = 0; i < CHUNK; ++i) {
    int idx = base + i;
    if (idx < N_NODES) mysum += deg[idx];
  }
  partial[t] = mysum;
  __syncthreads();
  for (int st = 1; st < 1024; st <<= 1) {
    int v = (t >= st) ? partial[t - st] : 0;
    __syncthreads();
    partial[t] += v;
    __syncthreads();
  }
  int run = partial[t] - mysum;
  for (int i = 0; i < CHUNK; ++i) {
    int idx = base + i;
    if (idx < N_NODES) {
      off[idx] = run;
      cursor[idx] = run;
      run += deg[idx];
    }
  }
  if (t == 1023) off[N_NODES] = N_EDGES;
}

__global__ __launch_bounds__(256) void fill_csr(const int* __restrict__ src,
                                                const int* __restrict__ dst,
                                                int* __restrict__ cursor,
                                                int* __restrict__ eidx) {
  for (int e = blockIdx.x * 256 + threadIdx.x; e < N_EDGES; e += gridDim.x * 256) {
    int p = atomicAdd(&cursor[dst[e]], 1);
    eidx[p] = src[e];
  }
}

// ------------------------------------------------- gather-aggregate -> node-block packed output
// Full-row version (layer 0, D=256). 16-deep edge unroll (mean degree 16) for MLP;
// clamped slots re-load the same row (L1 hit) and are masked to 0 — math unchanged.
template <int ROWF4, int HASBN>
__global__ __launch_bounds__(256) void agg_pk(const float4* __restrict__ h4,
                                              const int* __restrict__ off,
                                              const int* __restrict__ eidx,
                                              const float4* __restrict__ scale4,
                                              const float4* __restrict__ shift4,
                                              unsigned short* __restrict__ zp) {
  const int n = blockIdx.x * 4 + (threadIdx.x >> 6);
  if (n >= N_NODES) return;
  const int lane = threadIdx.x & 63;
  const int ROW = ROWF4 * 64;
  float4 sc[ROWF4], sh[ROWF4];
  if (HASBN) {
#pragma unroll
    for (int j = 0; j < ROWF4; ++j) {
      sc[j] = scale4[j * 64 + lane];
      sh[j] = shift4[j * 64 + lane];
    }
  }
  float4 v[ROWF4];
  const float4* hn = h4 + (long long)n * ROW;
#pragma unroll
  for (int j = 0; j < ROWF4; ++j) {
    float4 a = hn[j * 64 + lane];
    v[j] = HASBN ? bnrelu4(a, sc[j], sh[j]) : a;
  }

  int p = off[n];
  const int pe = off[n + 1];
  for (; p < pe; p += 16) {
    const float4* hp[16];
    float m[16];
#pragma unroll
    for (int e = 0; e < 16; ++e) {
      bool ok = (p + e) < pe;
      int idx = ok ? (p + e) : (pe - 1);  // clamp; pe-1 >= p >= 0 inside loop
      hp[e] = h4 + (long long)eidx[idx] * ROW;
      m[e] = ok ? 1.f : 0.f;
    }
#pragma unroll
    for (int j = 0; j < ROWF4; ++j) {
      float4 t[16];
#pragma unroll
      for (int e = 0; e < 16; ++e) {
        t[e] = hp[e][j * 64 + lane];
        if (HASBN) t[e] = bnrelu4(t[e], sc[j], sh[j]);
      }
#pragma unroll
      for (int e = 0; e < 16; ++e) {
        v[j].x = fmaf(t[e].x, m[e], v[j].x);
        v[j].y = fmaf(t[e].y, m[e], v[j].y);
        v[j].z = fmaf(t[e].z, m[e], v[j].z);
        v[j].w = fmaf(t[e].w, m[e], v[j].w);
      }
    }
  }
  const int nd = n & 63, tile = n >> 6;
#pragma unroll
  for (int j = 0; j < ROWF4; ++j) {
    int cj = j * 64 + lane;
    int ks = cj >> 3, k4 = cj & 7;
    size_t base = ((size_t)tile * (ROWF4 * 8) + ks) * 4096 + (size_t)nd * 32 +
                  (size_t)k4 * 4;
    split4_store(v[j], zp + base, zp + base + 2048);
  }
}

// ------------------------------------------------- channel-half gather-aggregate (D=512)
// SpMM feature-blocking (hot set 51 MB, L3-resident) + 16-deep edge unroll.
template <int HASBN>
__global__ __launch_bounds__(256) void agg_pk_half(const float4* __restrict__ h4,
                                                   const int* __restrict__ off,
                                                   const int* __restrict__ eidx,
                                                   const float4* __restrict__ scale4,
                                                   const float4* __restrict__ shift4,
                                                   unsigned short* __restrict__ zp,
                                                   int jsel) {
  const int n = blockIdx.x * 4 + (threadIdx.x >> 6);
  if (n >= N_NODES) return;
  const int lane = threadIdx.x & 63;
  const int ROW = 128;
  const int cj = jsel * 64 + lane;
  float4 sc, sh;
  if (HASBN) {
    sc = scale4[cj];
    sh = shift4[cj];
  }
  const float4* hn = h4 + (long long)n * ROW;
  float4 a0 = hn[cj];
  float4 v = HASBN ? bnrelu4(a0, sc, sh) : a0;

  int p = off[n];
  const int pe = off[n + 1];
  for (; p < pe; p += 16) {
    const float4* hp[16];
    float m[16];
#pragma unroll
    for (int e = 0; e < 16; ++e) {
      bool ok = (p + e) < pe;
      int idx = ok ? (p + e) : (pe - 1);
      hp[e] = h4 + (long long)eidx[idx] * ROW;
      m[e] = ok ? 1.f : 0.f;
    }
    float4 t[16];
#pragma unroll
    for (int e = 0; e < 16; ++e) {
      t[e] = hp[e][cj];
      if (HASBN) t[e] = bnrelu4(t[e], sc, sh);
    }
#pragma unroll
    for (int e = 0; e < 16; ++e) {
      v.x = fmaf(t[e].x, m[e], v.x);
      v.y = fmaf(t[e].y, m[e], v.y);
      v.z = fmaf(t[e].z, m[e], v.z);
      v.w = fmaf(t[e].w, m[e], v.w);
    }
  }
  const int nd = n & 63, tile = n >> 6;
  const int ks = cj >> 3, k4 = cj & 7;
  size_t base = ((size_t)tile * 16 + ks) * 4096 + (size_t)nd * 32 + (size_t)k4 * 4;
  split4_store(v, zp + base, zp + base + 2048);
}

// ------------------------------------------------- W pre-pack
__global__ __launch_bounds__(256) void wt_build(const float* __restrict__ W, // [K][512]
                                                unsigned short* __restrict__ Wp,
                                                int KS) {
  int gid = blockIdx.x * 256 + threadIdx.x;
  int total = 2 * KS * 8192;
  if (gid >= total) return;
  int blk = gid >> 13;
  int rem = gid & 8191;
  int cf = rem >> 9;
  int q = (rem >> 7) & 3;
  int c = (rem >> 3) & 15;
  int j = rem & 7;
  int bx = blk / KS, ks = blk - bx * KS;
  int chan = bx * 256 + cf * 16 + c;
  int k = ks * 32 + q * 8 + j;
  float v = W[(size_t)k * 512 + chan];
  unsigned short h, l;
  split_bf16(v, h, l);
  Wp[(size_t)blk * 16384 + rem] = h;
  Wp[(size_t)blk * 16384 + 8192 + rem] = l;
}

// ------------------------------------------------- LDS-free split-bf16 MFMA GEMM on node-block A,
// register double-buffered K pipeline. 1-D grid with XCD-pairing swizzle.
// (Best-measured GEMM config: Round-15 bench, ~172 us/dispatch.)
template <int KS, int STATS, int PACKOUT>
__global__ __launch_bounds__(256, 2) void gemm_pk(const unsigned short* __restrict__ Ap,
                                                  const unsigned short* __restrict__ Wp,
                                                  const float* __restrict__ bias,
                                                  float* __restrict__ Cf,
                                                  unsigned short* __restrict__ Cp,
                                                  float* __restrict__ stat_sum,
                                                  float* __restrict__ stat_sq,
                                                  int N, int NTtiles, int relu) {
  const int wg = blockIdx.x;
  const int bx = (wg >> 3) & 1;
  const int tile = (wg >> 4) * 8 + (wg & 7);
  if (tile >= NTtiles) return;
  const int tid = threadIdx.x;
  const int wv = tid >> 6, ln = tid & 63;
  const int n0 = tile * 64;
  const int q = ln >> 4, ccs = ln & 15;

  f32x4 acc[4][4];
#pragma unroll
  for (int i = 0; i < 4; ++i)
#pragma unroll
    for (int j = 0; j < 4; ++j) acc[i][j] = f32x4{0.f, 0.f, 0.f, 0.f};

  const unsigned short* wp =
      Wp + ((size_t)bx * KS) * 16384 + (size_t)(wv * 4) * 512 + (size_t)ln * 8;
  const unsigned short* ap =
      Ap + (size_t)tile * KS * 4096 + (size_t)ccs * 32 + (size_t)q * 8;

  bf16x8 wh[2][4], wl[2][4], ah[2][4], al[2][4];

#define LOADSTG(B, KSI)                                      \
  {                                                          \
    const unsigned short* w_ = wp + (size_t)(KSI) * 16384;   \
    const unsigned short* a_ = ap + (size_t)(KSI) * 4096;    \
    _Pragma("unroll") for (int i_ = 0; i_ < 4; ++i_) {       \
      wh[B][i_] = *(const bf16x8*)(w_ + i_ * 512);           \
      wl[B][i_] = *(const bf16x8*)(w_ + 8192 + i_ * 512);    \
      ah[B][i_] = *(const bf16x8*)(a_ + i_ * 512);           \
      al[B][i_] = *(const bf16x8*)(a_ + 2048 + i_ * 512);    \
    }                                                        \
  }

  LOADSTG(0, 0)
#pragma unroll
  for (int ks = 0; ks < KS; ++ks) {
    const int cur = ks & 1;
    if (ks + 1 < KS) LOADSTG(cur ^ 1, ks + 1)
#pragma unroll
    for (int i = 0; i < 4; ++i)
#pragma unroll
      for (int j = 0; j < 4; ++j) {
        acc[i][j] = __builtin_amdgcn_mfma_f32_16x16x32_bf16(wh[cur][i], ah[cur][j], acc[i][j], 0, 0, 0);
        acc[i][j] = __builtin_amdgcn_mfma_f32_16x16x32_bf16(wh[cur][i], al[cur][j], acc[i][j], 0, 0, 0);
        acc[i][j] = __builtin_amdgcn_mfma_f32_16x16x32_bf16(wl[cur][i], ah[cur][j], acc[i][j], 0, 0, 0);
      }
  }
#undef LOADSTG

  // epilogue: acc row = chan ((ln>>4)*4+reg), col = node (ln&15)
  const int chanb = bx * 256 + wv * 64 + (ln >> 4) * 4;
  float4 s4[4], q4[4];
  if (STATS) {
#pragma unroll
    for (int i = 0; i < 4; ++i) {
      s4[i] = make_float4(0.f, 0.f, 0.f, 0.f);
      q4[i] = make_float4(0.f, 0.f, 0.f, 0.f);
    }
  }
#pragma unroll
  for (int j = 0; j < 4; ++j) {
    int node = n0 + j * 16 + (ln & 15);
    bool valid = node < N;
    int nd = node & 63;
    int tile2 = node >> 6;
#pragma unroll
    for (int i = 0; i < 4; ++i) {
      int chan = chanb + i * 16;
      float4 bv = *(const float4*)(bias + chan);
      f32x4 a = acc[i][j];
      float4 o;
      o.x = a[0] + bv.x;
      o.y = a[1] + bv.y;
      o.z = a[2] + bv.z;
      o.w = a[3] + bv.w;
      if (relu) {
        o.x = fmaxf(o.x, 0.f);
        o.y = fmaxf(o.y, 0.f);
        o.z = fmaxf(o.z, 0.f);
        o.w = fmaxf(o.w, 0.f);
      }
      if (PACKOUT) {
        if (valid) {
          size_t base = ((size_t)tile2 * 16 + (size_t)(chan >> 5)) * 4096 +
                        (size_t)nd * 32 + (size_t)(chan & 31);
          split4_store(o, Cp + base, Cp + base + 2048);
        }
      } else {
        if (valid) *(float4*)(Cf + (size_t)node * 512 + chan) = o;
        if (STATS) {
          if (!valid) o = make_float4(0.f, 0.f, 0.f, 0.f);
          s4[i].x += o.x; s4[i].y += o.y; s4[i].z += o.z; s4[i].w += o.w;
          q4[i].x += o.x * o.x; q4[i].y += o.y * o.y;
          q4[i].z += o.z * o.z; q4[i].w += o.w * o.w;
        }
      }
    }
  }
  if (STATS) {
#pragma unroll
    for (int i = 0; i < 4; ++i) {
#pragma unroll
      for (int mask = 1; mask < 16; mask <<= 1) {
        s4[i].x += __shfl_xor(s4[i].x, mask);
        s4[i].y += __shfl_xor(s4[i].y, mask);
        s4[i].z += __shfl_xor(s4[i].z, mask);
        s4[i].w += __shfl_xor(s4[i].w, mask);
        q4[i].x += __shfl_xor(q4[i].x, mask);
        q4[i].y += __shfl_xor(q4[i].y, mask);
        q4[i].z += __shfl_xor(q4[i].z, mask);
        q4[i].w += __shfl_xor(q4[i].w, mask);
      }
    }
    if ((ln & 15) == 0) {
#pragma unroll
      for (int i = 0; i < 4; ++i) {
        int chan = chanb + i * 16;
        atomicAdd(&stat_sum[chan + 0], s4[i].x);
        atomicAdd(&stat_sum[chan + 1], s4[i].y);
        atomicAdd(&stat_sum[chan + 2], s4[i].z);
        atomicAdd(&stat_sum[chan + 3], s4[i].w);
        atomicAdd(&stat_sq[chan + 0], q4[i].x);
        atomicAdd(&stat_sq[chan + 1], q4[i].y);
        atomicAdd(&stat_sq[chan + 2], q4[i].z);
        atomicAdd(&stat_sq[chan + 3], q4[i].w);
      }
    }
  }
}

// ------------------------------------------------- BN finalize
__global__ __launch_bounds__(512) void bn_finalize(const float* __restrict__ sum,
                                                   const float* __restrict__ sumsq,
                                                   const float* __restrict__ g,
                                                   const float* __restrict__ b,
                                                   float* __restrict__ scale,
                                                   float* __restrict__ shift) {
  const int c = threadIdx.x;
  const float invN = 1.0f / (float)N_NODES;
  float mu = sum[c] * invN;
  float var = sumsq[c] * invN - mu * mu;
  float sc = rsqrtf(var + BN_EPS) * g[c];
  scale[c] = sc;
  shift[c] = fmaf(-mu, sc, b[c]);
}

// ------------------------------------------------- pool bounds
__global__ __launch_bounds__(512) void pool_bounds(const int* __restrict__ batch,
                                                   int* __restrict__ gstart) {
  const int g = threadIdx.x;
  int lo = 0, hi = N_NODES;
  while (lo < hi) {
    int mid = (lo + hi) >> 1;
    if (batch[mid] < g) lo = mid + 1;
    else hi = mid;
  }
  gstart[g] = lo;
  if (g == 0) gstart[N_GRAPHS] = N_NODES;
}

// ------------------------------------------------- segmented add pool + fused BN -> node-block pack
__global__ __launch_bounds__(128) void gpool_bn(const float4* __restrict__ z4,
                                                const int* __restrict__ gstart,
                                                const float4* __restrict__ scale4,
                                                const float4* __restrict__ shift4,
                                                unsigned short* __restrict__ gpp) {
  const int g = blockIdx.x;
  const int t = threadIdx.x;
  const int s = gstart[g], e = gstart[g + 1];
  const float4 sc = scale4[t], sh = shift4[t];
  float4 acc = make_float4(0.f, 0.f, 0.f, 0.f);
  for (int n = s; n < e; ++n) {
    float4 v = bnrelu4(z4[(size_t)n * 128 + t], sc, sh);
    acc.x += v.x;
    acc.y += v.y;
    acc.z += v.z;
    acc.w += v.w;
  }
  const int tile = g >> 6, nd = g & 63;
  const int ks = t >> 3, k4 = t & 7;
  size_t base = ((size_t)tile * 16 + ks) * 4096 + (size_t)nd * 32 + (size_t)k4 * 4;
  split4_store(acc, gpp + base, gpp + base + 2048);
}

// ------------------------------------------------- classifier tail
__global__ __launch_bounds__(64) void clf2_softmax(const float* __restrict__ hidden,
                                                   const float* __restrict__ w2,
                                                   const float* __restrict__ b2,
                                                   float* __restrict__ out) {
  const int g = blockIdx.x;
  const int lane = threadIdx.x;
  float acc[10];
#pragma unroll
  for (int j = 0; j < 10; ++j) acc[j] = 0.f;
  for (int k = lane; k < HID; k += 64) {
    float hv = hidden[(long long)g * HID + k];
#pragma unroll
    for (int j = 0; j < 10; ++j) acc[j] += hv * w2[k * 10 + j];
  }
#pragma unroll
  for (int j = 0; j < 10; ++j) {
    for (int o = 32; o > 0; o >>= 1) acc[j] += __shfl_down(acc[j], o);
  }
  if (lane == 0) {
    float lg[10], pb[10];
    float mx = -1e30f;
#pragma unroll
    for (int j = 0; j < 10; ++j) {
      lg[j] = acc[j] + b2[j];
      mx = fmaxf(mx, lg[j]);
    }
    float se = 0.f;
#pragma unroll
    for (int j = 0; j < 10; ++j) {
      pb[j] = __expf(lg[j] - mx);
      se += pb[j];
    }
    float inv = 1.f / se;
    int am = 0;
    float best = lg[0];
#pragma unroll
    for (int j = 1; j < 10; ++j) {
      if (lg[j] > best) { best = lg[j]; am = j; }
    }
#pragma unroll
    for (int j = 0; j < 10; ++j) out[g * 10 + j] = lg[j];
#pragma unroll
    for (int j = 0; j < 10; ++j) out[N_GRAPHS * 10 + g * 10 + j] = pb[j] * inv;
    out[2 * N_GRAPHS * 10 + g] = (float)am;
#pragma unroll
    for (int j = 0; j < 10; ++j)
      out[2 * N_GRAPHS * 10 + N_GRAPHS + g * 10 + j] = (j == am) ? 1.f : 0.f;
  }
}

// ----------------------------------------------------------------- launch
extern "C" void kernel_launch(void* const* d_in, const int* in_sizes, int n_in,
                              void* d_out, int out_size, void* d_ws, size_t ws_size,
                              hipStream_t stream) {
  const float* x = (const float*)d_in[0];
  const int* src = (const int*)d_in[1];
  const int* dstE = src + N_EDGES;
  const int* batch = (const int*)d_in[2];
  const float* w0a = (const float*)d_in[3];
  const float* b0a = (const float*)d_in[4];
  const float* w0b = (const float*)d_in[5];
  const float* b0b = (const float*)d_in[6];
  const float* w1a = (const float*)d_in[7];
  const float* b1a = (const float*)d_in[8];
  const float* w1b = (const float*)d_in[9];
  const float* b1b = (const float*)d_in[10];
  const float* w2a = (const float*)d_in[11];
  const float* b2a = (const float*)d_in[12];
  const float* w2b = (const float*)d_in[13];
  const float* b2b = (const float*)d_in[14];
  const float* bng[3] = {(const float*)d_in[15], (const float*)d_in[17], (const float*)d_in[19]};
  const float* bnb[3] = {(const float*)d_in[16], (const float*)d_in[18], (const float*)d_in[20]};
  const float* clf_w1 = (const float*)d_in[21];
  const float* clf_b1 = (const float*)d_in[22];
  const float* clf_w2 = (const float*)d_in[23];
  const float* clf_b2 = (const float*)d_in[24];
  float* out = (float*)d_out;

  // ---- workspace layout (~218 MB)
  const long long BUF = 25624576LL;
  float* bufA = (float*)d_ws;
  float* bufB = bufA + BUF;
  float* bnsum = bufB + BUF;
  float* bnsq = bnsum + 512;
  float* scale = bnsq + 512;
  float* shift = scale + 512;
  unsigned short* gpPack = (unsigned short*)(shift + 512);
  float* hidden = (float*)(gpPack + 524288);
  unsigned short* wp0a = (unsigned short*)(hidden + 262144);
  unsigned short* wp0b = wp0a + 262144;
  unsigned short* wp1a = wp0b + 524288;
  unsigned short* wp1b = wp1a + 524288;
  unsigned short* wp2a = wp1b + 524288;
  unsigned short* wp2b = wp2a + 524288;
  unsigned short* wpc1 = wp2b + 524288;
  int* deg = (int*)(wpc1 + 524288);
  int* off = deg + N_NODES;
  int* cursor = off + N_NODES + 1;
  int* eidx = cursor + N_NODES;
  int* gstart = eidx + N_EDGES;

  // ---- build CSR + pool bounds
  hipMemsetAsync(deg, 0, N_NODES * sizeof(int), stream);
  hipLaunchKernelGGL(hist_dst, dim3(3125), dim3(256), 0, stream, dstE, deg);
  hipLaunchKernelGGL(scan_deg, dim3(1), dim3(1024), 0, stream, deg, off, cursor);
  hipLaunchKernelGGL(fill_csr, dim3(3125), dim3(256), 0, stream, src, dstE, cursor, eidx);
  hipLaunchKernelGGL(pool_bounds, dim3(1), dim3(512), 0, stream, batch, gstart);

  // ---- pre-pack weights
  hipLaunchKernelGGL(wt_build, dim3(512), dim3(256), 0, stream, w0a, wp0a, 8);
  hipLaunchKernelGGL(wt_build, dim3(1024), dim3(256), 0, stream, w0b, wp0b, 16);
  hipLaunchKernelGGL(wt_build, dim3(1024), dim3(256), 0, stream, w1a, wp1a, 16);
  hipLaunchKernelGGL(wt_build, dim3(1024), dim3(256), 0, stream, w1b, wp1b, 16);
  hipLaunchKernelGGL(wt_build, dim3(1024), dim3(256), 0, stream, w2a, wp2a, 16);
  hipLaunchKernelGGL(wt_build, dim3(1024), dim3(256), 0, stream, w2b, wp2b, 16);
  hipLaunchKernelGGL(wt_build, dim3(1024), dim3(256), 0, stream, clf_w1, wpc1, 16);

  const unsigned short* wpa[3] = {wp0a, wp1a, wp2a};
  const unsigned short* wpb[3] = {wp0b, wp1b, wp2b};
  const float* ba[3] = {b0a, b1a, b2a};
  const float* bb[3] = {b0b, b1b, b2b};

  const int NT = (N_NODES + 63) / 64;            // 782
  const int GB = ((NT + 7) / 8) * 16;            // 1568 (XCD-paired 1-D grid)
  const int nagg = (N_NODES + 3) / 4;

  float* P = bufA;
  float* Q = bufB;
  for (int layer = 0; layer < 3; ++layer) {
    if (layer == 0) {
      hipLaunchKernelGGL((agg_pk<1, 0>), dim3(nagg), dim3(256), 0, stream,
                         (const float4*)x, off, eidx, nullptr, nullptr,
                         (unsigned short*)Q);
    } else {
      hipLaunchKernelGGL((agg_pk_half<1>), dim3(nagg), dim3(256), 0, stream,
                         (const float4*)P, off, eidx, (const float4*)scale,
                         (const float4*)shift, (unsigned short*)Q, 0);
      hipLaunchKernelGGL((agg_pk_half<1>), dim3(nagg), dim3(256), 0, stream,
                         (const float4*)P, off, eidx, (const float4*)scale,
                         (const float4*)shift, (unsigned short*)Q, 1);
    }
    { float* t = P; P = Q; Q = t; }
    if (layer == 0) {
      hipLaunchKernelGGL((gemm_pk<8, 0, 1>), dim3(GB), dim3(256), 0, stream,
                         (const unsigned short*)P, wpa[layer], ba[layer],
                         (float*)nullptr, (unsigned short*)Q, nullptr, nullptr,
                         N_NODES, NT, 1);
    } else {
      hipLaunchKernelGGL((gemm_pk<16, 0, 1>), dim3(GB), dim3(256), 0, stream,
                         (const unsigned short*)P, wpa[layer], ba[layer],
                         (float*)nullptr, (unsigned short*)Q, nullptr, nullptr,
                         N_NODES, NT, 1);
    }
    { float* t = P; P = Q; Q = t; }
    hipMemsetAsync(bnsum, 0, 2 * 512 * sizeof(float), stream);
    hipLaunchKernelGGL((gemm_pk<16, 1, 0>), dim3(GB), dim3(256), 0, stream,
                       (const unsigned short*)P, wpb[layer], bb[layer],
                       Q, (unsigned short*)nullptr, bnsum, bnsq,
                       N_NODES, NT, 0);
    { float* t = P; P = Q; Q = t; }
    hipLaunchKernelGGL(bn_finalize, dim3(1), dim3(512), 0, stream,
                       bnsum, bnsq, bng[layer], bnb[layer], scale, shift);
  }

  hipLaunchKernelGGL(gpool_bn, dim3(N_GRAPHS), dim3(128), 0, stream,
                     (const float4*)P, gstart, (const float4*)scale,
                     (const float4*)shift, gpPack);
  hipLaunchKernelGGL((gemm_pk<16, 0, 0>), dim3(16), dim3(256), 0, stream,
                     (const unsigned short*)gpPack, wpc1, clf_b1,
                     hidden, (unsigned short*)nullptr, nullptr, nullptr,
                     N_GRAPHS, 8, 1);
  hipLaunchKernelGGL(clf2_softmax, dim3(N_GRAPHS), dim3(64), 0, stream,
                     hidden, clf_w2, clf_b2, out);
}

// Round 19
// 1613.626 us; speedup vs baseline: 1.1592x; 1.0040x over previous
//
#include <hip/hip_runtime.h>

#define N_NODES 50000
#define N_EDGES 800000
#define N_GRAPHS 512
#define IN_DIM 256
#define HID 512
#define BN_EPS 1e-5f

typedef __attribute__((ext_vector_type(8))) short bf16x8;
typedef __attribute__((ext_vector_type(4))) float f32x4;

__device__ inline void split_bf16(float a, unsigned short& hi, unsigned short& lo) {
  unsigned u = __float_as_uint(a);
  hi = (unsigned short)(u >> 16);
  float fh = __uint_as_float(u & 0xFFFF0000u);
  float r = a - fh;
  lo = (unsigned short)(__float_as_uint(r) >> 16);
}

__device__ inline void split4_store(float4 v, unsigned short* hip, unsigned short* lop) {
  unsigned short h0, h1, h2, h3, l0, l1, l2, l3;
  split_bf16(v.x, h0, l0);
  split_bf16(v.y, h1, l1);
  split_bf16(v.z, h2, l2);
  split_bf16(v.w, h3, l3);
  uint2 hv, lv;
  hv.x = (unsigned)h0 | ((unsigned)h1 << 16);
  hv.y = (unsigned)h2 | ((unsigned)h3 << 16);
  lv.x = (unsigned)l0 | ((unsigned)l1 << 16);
  lv.y = (unsigned)l2 | ((unsigned)l3 << 16);
  *(uint2*)hip = hv;
  *(uint2*)lop = lv;
}

__device__ inline float4 bnrelu4(float4 v, float4 s, float4 h) {
  float4 o;
  o.x = fmaxf(fmaf(v.x, s.x, h.x), 0.f);
  o.y = fmaxf(fmaf(v.y, s.y, h.y), 0.f);
  o.z = fmaxf(fmaf(v.z, s.z, h.z), 0.f);
  o.w = fmaxf(fmaf(v.w, s.w, h.w), 0.f);
  return o;
}

// ------------------------------------------------- CSR build
__global__ __launch_bounds__(256) void hist_dst(const int* __restrict__ dst,
                                                int* __restrict__ deg) {
  for (int e = blockIdx.x * 256 + threadIdx.x; e < N_EDGES; e += gridDim.x * 256)
    atomicAdd(&deg[dst[e]], 1);
}

// exclusive scan (single block) + pool bounds folded into idle lanes
__global__ __launch_bounds__(1024) void scan_deg(const int* __restrict__ deg,
                                                 int* __restrict__ off,
                                                 int* __restrict__ cursor,
                                                 const int* __restrict__ batch,
                                                 int* __restrict__ gstart) {
  __shared__ int partial[1024];
  const int t = threadIdx.x;
  if (t < 512) {  // independent: gstart[g] = lower_bound(batch, g)
    int lo = 0, hi = N_NODES;
    while (lo < hi) {
      int mid = (lo + hi) >> 1;
      if (batch[mid] < t) lo = mid + 1;
      else hi = mid;
    }
    gstart[t] = lo;
    if (t == 0) gstart[N_GRAPHS] = N_NODES;
  }
  const int CHUNK = 49;
  const int base = t * CHUNK;
  int mysum = 0;
  for (int i = 0; i < CHUNK; ++i) {
    int idx = base + i;
    if (idx < N_NODES) mysum += deg[idx];
  }
  partial[t] = mysum;
  __syncthreads();
  for (int st = 1; st < 1024; st <<= 1) {
    int v = (t >= st) ? partial[t - st] : 0;
    __syncthreads();
    partial[t] += v;
    __syncthreads();
  }
  int run = partial[t] - mysum;
  for (int i = 0; i < CHUNK; ++i) {
    int idx = base + i;
    if (idx < N_NODES) {
      off[idx] = run;
      cursor[idx] = run;
      run += deg[idx];
    }
  }
  if (t == 1023) off[N_NODES] = N_EDGES;
}

__global__ __launch_bounds__(256) void fill_csr(const int* __restrict__ src,
                                                const int* __restrict__ dst,
                                                int* __restrict__ cursor,
                                                int* __restrict__ eidx) {
  for (int e = blockIdx.x * 256 + threadIdx.x; e < N_EDGES; e += gridDim.x * 256) {
    int p = atomicAdd(&cursor[dst[e]], 1);
    eidx[p] = src[e];
  }
}

// ------------------------------------------------- gather-aggregate -> node-block packed output
// Full-row version (layer 0, D=256). 16-deep edge unroll; clamped slots masked to 0.
template <int ROWF4, int HASBN>
__global__ __launch_bounds__(256) void agg_pk(const float4* __restrict__ h4,
                                              const int* __restrict__ off,
                                              const int* __restrict__ eidx,
                                              const float4* __restrict__ scale4,
                                              const float4* __restrict__ shift4,
                                              unsigned short* __restrict__ zp) {
  const int n = blockIdx.x * 4 + (threadIdx.x >> 6);
  if (n >= N_NODES) return;
  const int lane = threadIdx.x & 63;
  const int ROW = ROWF4 * 64;
  float4 sc[ROWF4], sh[ROWF4];
  if (HASBN) {
#pragma unroll
    for (int j = 0; j < ROWF4; ++j) {
      sc[j] = scale4[j * 64 + lane];
      sh[j] = shift4[j * 64 + lane];
    }
  }
  float4 v[ROWF4];
  const float4* hn = h4 + (long long)n * ROW;
#pragma unroll
  for (int j = 0; j < ROWF4; ++j) {
    float4 a = hn[j * 64 + lane];
    v[j] = HASBN ? bnrelu4(a, sc[j], sh[j]) : a;
  }

  int p = off[n];
  const int pe = off[n + 1];
  for (; p < pe; p += 16) {
    const float4* hp[16];
    float m[16];
#pragma unroll
    for (int e = 0; e < 16; ++e) {
      bool ok = (p + e) < pe;
      int idx = ok ? (p + e) : (pe - 1);
      hp[e] = h4 + (long long)eidx[idx] * ROW;
      m[e] = ok ? 1.f : 0.f;
    }
#pragma unroll
    for (int j = 0; j < ROWF4; ++j) {
      float4 t[16];
#pragma unroll
      for (int e = 0; e < 16; ++e) {
        t[e] = hp[e][j * 64 + lane];
        if (HASBN) t[e] = bnrelu4(t[e], sc[j], sh[j]);
      }
#pragma unroll
      for (int e = 0; e < 16; ++e) {
        v[j].x = fmaf(t[e].x, m[e], v[j].x);
        v[j].y = fmaf(t[e].y, m[e], v[j].y);
        v[j].z = fmaf(t[e].z, m[e], v[j].z);
        v[j].w = fmaf(t[e].w, m[e], v[j].w);
      }
    }
  }
  const int nd = n & 63, tile = n >> 6;
#pragma unroll
  for (int j = 0; j < ROWF4; ++j) {
    int cj = j * 64 + lane;
    int ks = cj >> 3, k4 = cj & 7;
    size_t base = ((size_t)tile * (ROWF4 * 8) + ks) * 4096 + (size_t)nd * 32 +
                  (size_t)k4 * 4;
    split4_store(v[j], zp + base, zp + base + 2048);
  }
}

// ------------------------------------------------- channel-half gather-aggregate (D=512)
template <int HASBN>
__global__ __launch_bounds__(256) void agg_pk_half(const float4* __restrict__ h4,
                                                   const int* __restrict__ off,
                                                   const int* __restrict__ eidx,
                                                   const float4* __restrict__ scale4,
                                                   const float4* __restrict__ shift4,
                                                   unsigned short* __restrict__ zp,
                                                   int jsel) {
  const int n = blockIdx.x * 4 + (threadIdx.x >> 6);
  if (n >= N_NODES) return;
  const int lane = threadIdx.x & 63;
  const int ROW = 128;
  const int cj = jsel * 64 + lane;
  float4 sc, sh;
  if (HASBN) {
    sc = scale4[cj];
    sh = shift4[cj];
  }
  const float4* hn = h4 + (long long)n * ROW;
  float4 a0 = hn[cj];
  float4 v = HASBN ? bnrelu4(a0, sc, sh) : a0;

  int p = off[n];
  const int pe = off[n + 1];
  for (; p < pe; p += 16) {
    const float4* hp[16];
    float m[16];
#pragma unroll
    for (int e = 0; e < 16; ++e) {
      bool ok = (p + e) < pe;
      int idx = ok ? (p + e) : (pe - 1);
      hp[e] = h4 + (long long)eidx[idx] * ROW;
      m[e] = ok ? 1.f : 0.f;
    }
    float4 t[16];
#pragma unroll
    for (int e = 0; e < 16; ++e) {
      t[e] = hp[e][cj];
      if (HASBN) t[e] = bnrelu4(t[e], sc, sh);
    }
#pragma unroll
    for (int e = 0; e < 16; ++e) {
      v.x = fmaf(t[e].x, m[e], v.x);
      v.y = fmaf(t[e].y, m[e], v.y);
      v.z = fmaf(t[e].z, m[e], v.z);
      v.w = fmaf(t[e].w, m[e], v.w);
    }
  }
  const int nd = n & 63, tile = n >> 6;
  const int ks = cj >> 3, k4 = cj & 7;
  size_t base = ((size_t)tile * 16 + ks) * 4096 + (size_t)nd * 32 + (size_t)k4 * 4;
  split4_store(v, zp + base, zp + base + 2048);
}

// ------------------------------------------------- W pre-pack: ALL weights in one launch.
// Segment 0: w0a (KS=8, 131072 elems); segments 1..6: KS=16, 262144 elems each.
__global__ __launch_bounds__(256) void wt_build_all(
    const float* __restrict__ w0a, const float* __restrict__ w0b,
    const float* __restrict__ w1a, const float* __restrict__ w1b,
    const float* __restrict__ w2a, const float* __restrict__ w2b,
    const float* __restrict__ wc1,
    unsigned short* __restrict__ p0a, unsigned short* __restrict__ p0b,
    unsigned short* __restrict__ p1a, unsigned short* __restrict__ p1b,
    unsigned short* __restrict__ p2a, unsigned short* __restrict__ p2b,
    unsigned short* __restrict__ pc1) {
  int gid = blockIdx.x * 256 + threadIdx.x;
  const float* W;
  unsigned short* Wp;
  int KS, lg;
  if (gid < 131072) {
    W = w0a; Wp = p0a; KS = 8; lg = gid;
  } else {
    int g2 = gid - 131072;
    int seg = g2 >> 18;  // 262144 = 2^18
    lg = g2 & 262143;
    KS = 16;
    if (seg == 0) { W = w0b; Wp = p0b; }
    else if (seg == 1) { W = w1a; Wp = p1a; }
    else if (seg == 2) { W = w1b; Wp = p1b; }
    else if (seg == 3) { W = w2a; Wp = p2a; }
    else if (seg == 4) { W = w2b; Wp = p2b; }
    else if (seg == 5) { W = wc1; Wp = pc1; }
    else return;
  }
  int blk = lg >> 13;
  int rem = lg & 8191;
  int cf = rem >> 9;
  int q = (rem >> 7) & 3;
  int c = (rem >> 3) & 15;
  int j = rem & 7;
  int bx = blk / KS, ks = blk - bx * KS;
  int chan = bx * 256 + cf * 16 + c;
  int k = ks * 32 + q * 8 + j;
  float v = W[(size_t)k * 512 + chan];
  unsigned short h, l;
  split_bf16(v, h, l);
  Wp[(size_t)blk * 16384 + rem] = h;
  Wp[(size_t)blk * 16384 + 8192 + rem] = l;
}

// ------------------------------------------------- LDS-free split-bf16 MFMA GEMM on node-block A,
// register double-buffered K pipeline. 1-D grid with XCD-pairing swizzle. (Best-measured config.)
template <int KS, int STATS, int PACKOUT>
__global__ __launch_bounds__(256, 2) void gemm_pk(const unsigned short* __restrict__ Ap,
                                                  const unsigned short* __restrict__ Wp,
                                                  const float* __restrict__ bias,
                                                  float* __restrict__ Cf,
                                                  unsigned short* __restrict__ Cp,
                                                  float* __restrict__ stat_sum,
                                                  float* __restrict__ stat_sq,
                                                  int N, int NTtiles, int relu) {
  const int wg = blockIdx.x;
  const int bx = (wg >> 3) & 1;
  const int tile = (wg >> 4) * 8 + (wg & 7);
  if (tile >= NTtiles) return;
  const int tid = threadIdx.x;
  const int wv = tid >> 6, ln = tid & 63;
  const int n0 = tile * 64;
  const int q = ln >> 4, ccs = ln & 15;

  f32x4 acc[4][4];
#pragma unroll
  for (int i = 0; i < 4; ++i)
#pragma unroll
    for (int j = 0; j < 4; ++j) acc[i][j] = f32x4{0.f, 0.f, 0.f, 0.f};

  const unsigned short* wp =
      Wp + ((size_t)bx * KS) * 16384 + (size_t)(wv * 4) * 512 + (size_t)ln * 8;
  const unsigned short* ap =
      Ap + (size_t)tile * KS * 4096 + (size_t)ccs * 32 + (size_t)q * 8;

  bf16x8 wh[2][4], wl[2][4], ah[2][4], al[2][4];

#define LOADSTG(B, KSI)                                      \
  {                                                          \
    const unsigned short* w_ = wp + (size_t)(KSI) * 16384;   \
    const unsigned short* a_ = ap + (size_t)(KSI) * 4096;    \
    _Pragma("unroll") for (int i_ = 0; i_ < 4; ++i_) {       \
      wh[B][i_] = *(const bf16x8*)(w_ + i_ * 512);           \
      wl[B][i_] = *(const bf16x8*)(w_ + 8192 + i_ * 512);    \
      ah[B][i_] = *(const bf16x8*)(a_ + i_ * 512);           \
      al[B][i_] = *(const bf16x8*)(a_ + 2048 + i_ * 512);    \
    }                                                        \
  }

  LOADSTG(0, 0)
#pragma unroll
  for (int ks = 0; ks < KS; ++ks) {
    const int cur = ks & 1;
    if (ks + 1 < KS) LOADSTG(cur ^ 1, ks + 1)
#pragma unroll
    for (int i = 0; i < 4; ++i)
#pragma unroll
      for (int j = 0; j < 4; ++j) {
        acc[i][j] = __builtin_amdgcn_mfma_f32_16x16x32_bf16(wh[cur][i], ah[cur][j], acc[i][j], 0, 0, 0);
        acc[i][j] = __builtin_amdgcn_mfma_f32_16x16x32_bf16(wh[cur][i], al[cur][j], acc[i][j], 0, 0, 0);
        acc[i][j] = __builtin_amdgcn_mfma_f32_16x16x32_bf16(wl[cur][i], ah[cur][j], acc[i][j], 0, 0, 0);
      }
  }
#undef LOADSTG

  // epilogue: acc row = chan ((ln>>4)*4+reg), col = node (ln&15)
  const int chanb = bx * 256 + wv * 64 + (ln >> 4) * 4;
  float4 s4[4], q4[4];
  if (STATS) {
#pragma unroll
    for (int i = 0; i < 4; ++i) {
      s4[i] = make_float4(0.f, 0.f, 0.f, 0.f);
      q4[i] = make_float4(0.f, 0.f, 0.f, 0.f);
    }
  }
#pragma unroll
  for (int j = 0; j < 4; ++j) {
    int node = n0 + j * 16 + (ln & 15);
    bool valid = node < N;
    int nd = node & 63;
    int tile2 = node >> 6;
#pragma unroll
    for (int i = 0; i < 4; ++i) {
      int chan = chanb + i * 16;
      float4 bv = *(const float4*)(bias + chan);
      f32x4 a = acc[i][j];
      float4 o;
      o.x = a[0] + bv.x;
      o.y = a[1] + bv.y;
      o.z = a[2] + bv.z;
      o.w = a[3] + bv.w;
      if (relu) {
        o.x = fmaxf(o.x, 0.f);
        o.y = fmaxf(o.y, 0.f);
        o.z = fmaxf(o.z, 0.f);
        o.w = fmaxf(o.w, 0.f);
      }
      if (PACKOUT) {
        if (valid) {
          size_t base = ((size_t)tile2 * 16 + (size_t)(chan >> 5)) * 4096 +
                        (size_t)nd * 32 + (size_t)(chan & 31);
          split4_store(o, Cp + base, Cp + base + 2048);
        }
      } else {
        if (valid) *(float4*)(Cf + (size_t)node * 512 + chan) = o;
        if (STATS) {
          if (!valid) o = make_float4(0.f, 0.f, 0.f, 0.f);
          s4[i].x += o.x; s4[i].y += o.y; s4[i].z += o.z; s4[i].w += o.w;
          q4[i].x += o.x * o.x; q4[i].y += o.y * o.y;
          q4[i].z += o.z * o.z; q4[i].w += o.w * o.w;
        }
      }
    }
  }
  if (STATS) {
#pragma unroll
    for (int i = 0; i < 4; ++i) {
#pragma unroll
      for (int mask = 1; mask < 16; mask <<= 1) {
        s4[i].x += __shfl_xor(s4[i].x, mask);
        s4[i].y += __shfl_xor(s4[i].y, mask);
        s4[i].z += __shfl_xor(s4[i].z, mask);
        s4[i].w += __shfl_xor(s4[i].w, mask);
        q4[i].x += __shfl_xor(q4[i].x, mask);
        q4[i].y += __shfl_xor(q4[i].y, mask);
        q4[i].z += __shfl_xor(q4[i].z, mask);
        q4[i].w += __shfl_xor(q4[i].w, mask);
      }
    }
    if ((ln & 15) == 0) {
#pragma unroll
      for (int i = 0; i < 4; ++i) {
        int chan = chanb + i * 16;
        atomicAdd(&stat_sum[chan + 0], s4[i].x);
        atomicAdd(&stat_sum[chan + 1], s4[i].y);
        atomicAdd(&stat_sum[chan + 2], s4[i].z);
        atomicAdd(&stat_sum[chan + 3], s4[i].w);
        atomicAdd(&stat_sq[chan + 0], q4[i].x);
        atomicAdd(&stat_sq[chan + 1], q4[i].y);
        atomicAdd(&stat_sq[chan + 2], q4[i].z);
        atomicAdd(&stat_sq[chan + 3], q4[i].w);
      }
    }
  }
}

// ------------------------------------------------- BN finalize
__global__ __launch_bounds__(512) void bn_finalize(const float* __restrict__ sum,
                                                   const float* __restrict__ sumsq,
                                                   const float* __restrict__ g,
                                                   const float* __restrict__ b,
                                                   float* __restrict__ scale,
                                                   float* __restrict__ shift) {
  const int c = threadIdx.x;
  const float invN = 1.0f / (float)N_NODES;
  float mu = sum[c] * invN;
  float var = sumsq[c] * invN - mu * mu;
  float sc = rsqrtf(var + BN_EPS) * g[c];
  scale[c] = sc;
  shift[c] = fmaf(-mu, sc, b[c]);
}

// ------------------------------------------------- segmented add pool + fused BN -> node-block pack
__global__ __launch_bounds__(128) void gpool_bn(const float4* __restrict__ z4,
                                                const int* __restrict__ gstart,
                                                const float4* __restrict__ scale4,
                                                const float4* __restrict__ shift4,
                                                unsigned short* __restrict__ gpp) {
  const int g = blockIdx.x;
  const int t = threadIdx.x;
  const int s = gstart[g], e = gstart[g + 1];
  const float4 sc = scale4[t], sh = shift4[t];
  float4 acc = make_float4(0.f, 0.f, 0.f, 0.f);
  for (int n = s; n < e; ++n) {
    float4 v = bnrelu4(z4[(size_t)n * 128 + t], sc, sh);
    acc.x += v.x;
    acc.y += v.y;
    acc.z += v.z;
    acc.w += v.w;
  }
  const int tile = g >> 6, nd = g & 63;
  const int ks = t >> 3, k4 = t & 7;
  size_t base = ((size_t)tile * 16 + ks) * 4096 + (size_t)nd * 32 + (size_t)k4 * 4;
  split4_store(acc, gpp + base, gpp + base + 2048);
}

// ------------------------------------------------- classifier tail
__global__ __launch_bounds__(64) void clf2_softmax(const float* __restrict__ hidden,
                                                   const float* __restrict__ w2,
                                                   const float* __restrict__ b2,
                                                   float* __restrict__ out) {
  const int g = blockIdx.x;
  const int lane = threadIdx.x;
  float acc[10];
#pragma unroll
  for (int j = 0; j < 10; ++j) acc[j] = 0.f;
  for (int k = lane; k < HID; k += 64) {
    float hv = hidden[(long long)g * HID + k];
#pragma unroll
    for (int j = 0; j < 10; ++j) acc[j] += hv * w2[k * 10 + j];
  }
#pragma unroll
  for (int j = 0; j < 10; ++j) {
    for (int o = 32; o > 0; o >>= 1) acc[j] += __shfl_down(acc[j], o);
  }
  if (lane == 0) {
    float lg[10], pb[10];
    float mx = -1e30f;
#pragma unroll
    for (int j = 0; j < 10; ++j) {
      lg[j] = acc[j] + b2[j];
      mx = fmaxf(mx, lg[j]);
    }
    float se = 0.f;
#pragma unroll
    for (int j = 0; j < 10; ++j) {
      pb[j] = __expf(lg[j] - mx);
      se += pb[j];
    }
    float inv = 1.f / se;
    int am = 0;
    float best = lg[0];
#pragma unroll
    for (int j = 1; j < 10; ++j) {
      if (lg[j] > best) { best = lg[j]; am = j; }
    }
#pragma unroll
    for (int j = 0; j < 10; ++j) out[g * 10 + j] = lg[j];
#pragma unroll
    for (int j = 0; j < 10; ++j) out[N_GRAPHS * 10 + g * 10 + j] = pb[j] * inv;
    out[2 * N_GRAPHS * 10 + g] = (float)am;
#pragma unroll
    for (int j = 0; j < 10; ++j)
      out[2 * N_GRAPHS * 10 + N_GRAPHS + g * 10 + j] = (j == am) ? 1.f : 0.f;
  }
}

// ----------------------------------------------------------------- launch
extern "C" void kernel_launch(void* const* d_in, const int* in_sizes, int n_in,
                              void* d_out, int out_size, void* d_ws, size_t ws_size,
                              hipStream_t stream) {
  const float* x = (const float*)d_in[0];
  const int* src = (const int*)d_in[1];
  const int* dstE = src + N_EDGES;
  const int* batch = (const int*)d_in[2];
  const float* w0a = (const float*)d_in[3];
  const float* b0a = (const float*)d_in[4];
  const float* w0b = (const float*)d_in[5];
  const float* b0b = (const float*)d_in[6];
  const float* w1a = (const float*)d_in[7];
  const float* b1a = (const float*)d_in[8];
  const float* w1b = (const float*)d_in[9];
  const float* b1b = (const float*)d_in[10];
  const float* w2a = (const float*)d_in[11];
  const float* b2a = (const float*)d_in[12];
  const float* w2b = (const float*)d_in[13];
  const float* b2b = (const float*)d_in[14];
  const float* bng[3] = {(const float*)d_in[15], (const float*)d_in[17], (const float*)d_in[19]};
  const float* bnb[3] = {(const float*)d_in[16], (const float*)d_in[18], (const float*)d_in[20]};
  const float* clf_w1 = (const float*)d_in[21];
  const float* clf_b1 = (const float*)d_in[22];
  const float* clf_w2 = (const float*)d_in[23];
  const float* clf_b2 = (const float*)d_in[24];
  float* out = (float*)d_out;

  // ---- workspace layout (~218 MB); deg + per-layer bn stats contiguous for one memset
  const long long BUF = 25624576LL;
  float* bufA = (float*)d_ws;
  float* bufB = bufA + BUF;
  float* scale = bufB + BUF;          // 512
  float* shift = scale + 512;         // 512
  unsigned short* gpPack = (unsigned short*)(shift + 512);  // 524288 ushorts
  float* hidden = (float*)(gpPack + 524288);                // 262144 floats
  unsigned short* wp0a = (unsigned short*)(hidden + 262144);
  unsigned short* wp0b = wp0a + 262144;
  unsigned short* wp1a = wp0b + 524288;
  unsigned short* wp1b = wp1a + 524288;
  unsigned short* wp2a = wp1b + 524288;
  unsigned short* wp2b = wp2a + 524288;
  unsigned short* wpc1 = wp2b + 524288;
  int* deg = (int*)(wpc1 + 524288);        // 50000  (zero region start)
  float* bnsum = (float*)(deg + N_NODES);  // 3*512
  float* bnsq = bnsum + 3 * 512;           // 3*512  (zero region end)
  int* off = (int*)(bnsq + 3 * 512);       // 50001
  int* cursor = off + N_NODES + 1;         // 50000
  int* eidx = cursor + N_NODES;            // 800000
  int* gstart = eidx + N_EDGES;            // 513

  // ---- one memset for deg + all per-layer bn stats
  hipMemsetAsync(deg, 0, (N_NODES + 6 * 512) * sizeof(int), stream);
  // ---- CSR build + pool bounds (folded) + single weight pre-pack launch
  hipLaunchKernelGGL(hist_dst, dim3(3125), dim3(256), 0, stream, dstE, deg);
  hipLaunchKernelGGL(scan_deg, dim3(1), dim3(1024), 0, stream, deg, off, cursor, batch, gstart);
  hipLaunchKernelGGL(fill_csr, dim3(3125), dim3(256), 0, stream, src, dstE, cursor, eidx);
  hipLaunchKernelGGL(wt_build_all, dim3(6656), dim3(256), 0, stream,
                     w0a, w0b, w1a, w1b, w2a, w2b, clf_w1,
                     wp0a, wp0b, wp1a, wp1b, wp2a, wp2b, wpc1);

  const unsigned short* wpa[3] = {wp0a, wp1a, wp2a};
  const unsigned short* wpb[3] = {wp0b, wp1b, wp2b};
  const float* ba[3] = {b0a, b1a, b2a};
  const float* bb[3] = {b0b, b1b, b2b};

  const int NT = (N_NODES + 63) / 64;            // 782
  const int GB = ((NT + 7) / 8) * 16;            // 1568 (XCD-paired 1-D grid)
  const int nagg = (N_NODES + 3) / 4;

  float* P = bufA;
  float* Q = bufB;
  for (int layer = 0; layer < 3; ++layer) {
    if (layer == 0) {
      hipLaunchKernelGGL((agg_pk<1, 0>), dim3(nagg), dim3(256), 0, stream,
                         (const float4*)x, off, eidx, nullptr, nullptr,
                         (unsigned short*)Q);
    } else {
      hipLaunchKernelGGL((agg_pk_half<1>), dim3(nagg), dim3(256), 0, stream,
                         (const float4*)P, off, eidx, (const float4*)scale,
                         (const float4*)shift, (unsigned short*)Q, 0);
      hipLaunchKernelGGL((agg_pk_half<1>), dim3(nagg), dim3(256), 0, stream,
                         (const float4*)P, off, eidx, (const float4*)scale,
                         (const float4*)shift, (unsigned short*)Q, 1);
    }
    { float* t = P; P = Q; Q = t; }
    if (layer == 0) {
      hipLaunchKernelGGL((gemm_pk<8, 0, 1>), dim3(GB), dim3(256), 0, stream,
                         (const unsigned short*)P, wpa[layer], ba[layer],
                         (float*)nullptr, (unsigned short*)Q, nullptr, nullptr,
                         N_NODES, NT, 1);
    } else {
      hipLaunchKernelGGL((gemm_pk<16, 0, 1>), dim3(GB), dim3(256), 0, stream,
                         (const unsigned short*)P, wpa[layer], ba[layer],
                         (float*)nullptr, (unsigned short*)Q, nullptr, nullptr,
                         N_NODES, NT, 1);
    }
    { float* t = P; P = Q; Q = t; }
    // per-layer stat slots (pre-zeroed once)
    hipLaunchKernelGGL((gemm_pk<16, 1, 0>), dim3(GB), dim3(256), 0, stream,
                       (const unsigned short*)P, wpb[layer], bb[layer],
                       Q, (unsigned short*)nullptr, bnsum + layer * 512, bnsq + layer * 512,
                       N_NODES, NT, 0);
    { float* t = P; P = Q; Q = t; }
    hipLaunchKernelGGL(bn_finalize, dim3(1), dim3(512), 0, stream,
                       bnsum + layer * 512, bnsq + layer * 512,
                       bng[layer], bnb[layer], scale, shift);
  }

  hipLaunchKernelGGL(gpool_bn, dim3(N_GRAPHS), dim3(128), 0, stream,
                     (const float4*)P, gstart, (const float4*)scale,
                     (const float4*)shift, gpPack);
  hipLaunchKernelGGL((gemm_pk<16, 0, 0>), dim3(16), dim3(256), 0, stream,
                     (const unsigned short*)gpPack, wpc1, clf_b1,
                     hidden, (unsigned short*)nullptr, nullptr, nullptr,
                     N_GRAPHS, 8, 1);
  hipLaunchKernelGGL(clf2_softmax, dim3(N_GRAPHS), dim3(64), 0, stream,
                     hidden, clf_w2, clf_b2, out);
}

// Round 20
// 1551.793 us; speedup vs baseline: 1.2054x; 1.0398x over previous
//
#include <hip/hip_runtime.h>

#define N_NODES 50000
#define N_EDGES 800000
#define N_GRAPHS 512
#define IN_DIM 256
#define HID 512
#define BN_EPS 1e-5f

typedef __attribute__((ext_vector_type(8))) short bf16x8;
typedef __attribute__((ext_vector_type(4))) float f32x4;

__device__ inline void split_bf16(float a, unsigned short& hi, unsigned short& lo) {
  unsigned u = __float_as_uint(a);
  hi = (unsigned short)(u >> 16);
  float fh = __uint_as_float(u & 0xFFFF0000u);
  float r = a - fh;
  lo = (unsigned short)(__float_as_uint(r) >> 16);
}

__device__ inline void split4_store(float4 v, unsigned short* hip, unsigned short* lop) {
  unsigned short h0, h1, h2, h3, l0, l1, l2, l3;
  split_bf16(v.x, h0, l0);
  split_bf16(v.y, h1, l1);
  split_bf16(v.z, h2, l2);
  split_bf16(v.w, h3, l3);
  uint2 hv, lv;
  hv.x = (unsigned)h0 | ((unsigned)h1 << 16);
  hv.y = (unsigned)h2 | ((unsigned)h3 << 16);
  lv.x = (unsigned)l0 | ((unsigned)l1 << 16);
  lv.y = (unsigned)l2 | ((unsigned)l3 << 16);
  *(uint2*)hip = hv;
  *(uint2*)lop = lv;
}

__device__ inline float4 bnrelu4(float4 v, float4 s, float4 h) {
  float4 o;
  o.x = fmaxf(fmaf(v.x, s.x, h.x), 0.f);
  o.y = fmaxf(fmaf(v.y, s.y, h.y), 0.f);
  o.z = fmaxf(fmaf(v.z, s.z, h.z), 0.f);
  o.w = fmaxf(fmaf(v.w, s.w, h.w), 0.f);
  return o;
}

// ------------------------------------------------- CSR build
__global__ __launch_bounds__(256) void hist_dst(const int* __restrict__ dst,
                                                int* __restrict__ deg) {
  for (int e = blockIdx.x * 256 + threadIdx.x; e < N_EDGES; e += gridDim.x * 256)
    atomicAdd(&deg[dst[e]], 1);
}

// exclusive scan (single block) + pool bounds folded into idle lanes
__global__ __launch_bounds__(1024) void scan_deg(const int* __restrict__ deg,
                                                 int* __restrict__ off,
                                                 int* __restrict__ cursor,
                                                 const int* __restrict__ batch,
                                                 int* __restrict__ gstart) {
  __shared__ int partial[1024];
  const int t = threadIdx.x;
  if (t < 512) {
    int lo = 0, hi = N_NODES;
    while (lo < hi) {
      int mid = (lo + hi) >> 1;
      if (batch[mid] < t) lo = mid + 1;
      else hi = mid;
    }
    gstart[t] = lo;
    if (t == 0) gstart[N_GRAPHS] = N_NODES;
  }
  const int CHUNK = 49;
  const int base = t * CHUNK;
  int mysum = 0;
  for (int i = 0; i < CHUNK; ++i) {
    int idx = base + i;
    if (idx < N_NODES) mysum += deg[idx];
  }
  partial[t] = mysum;
  __syncthreads();
  for (int st = 1; st < 1024; st <<= 1) {
    int v = (t >= st) ? partial[t - st] : 0;
    __syncthreads();
    partial[t] += v;
    __syncthreads();
  }
  int run = partial[t] - mysum;
  for (int i = 0; i < CHUNK; ++i) {
    int idx = base + i;
    if (idx < N_NODES) {
      off[idx] = run;
      cursor[idx] = run;
      run += deg[idx];
    }
  }
  if (t == 1023) off[N_NODES] = N_EDGES;
}

__global__ __launch_bounds__(256) void fill_csr(const int* __restrict__ src,
                                                const int* __restrict__ dst,
                                                int* __restrict__ cursor,
                                                int* __restrict__ eidx) {
  for (int e = blockIdx.x * 256 + threadIdx.x; e < N_EDGES; e += gridDim.x * 256) {
    int p = atomicAdd(&cursor[dst[e]], 1);
    eidx[p] = src[e];
  }
}

// ------------------------------------------------- gather-aggregate -> node-block packed output
// Full-row version (layer 0, D=256). 16-deep edge unroll; clamped slots masked to 0.
template <int ROWF4, int HASBN>
__global__ __launch_bounds__(256) void agg_pk(const float4* __restrict__ h4,
                                              const int* __restrict__ off,
                                              const int* __restrict__ eidx,
                                              const float4* __restrict__ scale4,
                                              const float4* __restrict__ shift4,
                                              unsigned short* __restrict__ zp) {
  const int n = blockIdx.x * 4 + (threadIdx.x >> 6);
  if (n >= N_NODES) return;
  const int lane = threadIdx.x & 63;
  const int ROW = ROWF4 * 64;
  float4 sc[ROWF4], sh[ROWF4];
  if (HASBN) {
#pragma unroll
    for (int j = 0; j < ROWF4; ++j) {
      sc[j] = scale4[j * 64 + lane];
      sh[j] = shift4[j * 64 + lane];
    }
  }
  float4 v[ROWF4];
  const float4* hn = h4 + (long long)n * ROW;
#pragma unroll
  for (int j = 0; j < ROWF4; ++j) {
    float4 a = hn[j * 64 + lane];
    v[j] = HASBN ? bnrelu4(a, sc[j], sh[j]) : a;
  }

  int p = off[n];
  const int pe = off[n + 1];
  for (; p < pe; p += 16) {
    const float4* hp[16];
    float m[16];
#pragma unroll
    for (int e = 0; e < 16; ++e) {
      bool ok = (p + e) < pe;
      int idx = ok ? (p + e) : (pe - 1);
      hp[e] = h4 + (long long)eidx[idx] * ROW;
      m[e] = ok ? 1.f : 0.f;
    }
#pragma unroll
    for (int j = 0; j < ROWF4; ++j) {
      float4 t[16];
#pragma unroll
      for (int e = 0; e < 16; ++e) {
        t[e] = hp[e][j * 64 + lane];
        if (HASBN) t[e] = bnrelu4(t[e], sc[j], sh[j]);
      }
#pragma unroll
      for (int e = 0; e < 16; ++e) {
        v[j].x = fmaf(t[e].x, m[e], v[j].x);
        v[j].y = fmaf(t[e].y, m[e], v[j].y);
        v[j].z = fmaf(t[e].z, m[e], v[j].z);
        v[j].w = fmaf(t[e].w, m[e], v[j].w);
      }
    }
  }
  const int nd = n & 63, tile = n >> 6;
#pragma unroll
  for (int j = 0; j < ROWF4; ++j) {
    int cj = j * 64 + lane;
    int ks = cj >> 3, k4 = cj & 7;
    size_t base = ((size_t)tile * (ROWF4 * 8) + ks) * 4096 + (size_t)nd * 32 +
                  (size_t)k4 * 4;
    split4_store(v[j], zp + base, zp + base + 2048);
  }
}

// ------------------------------------------------- channel-half gather-aggregate (D=512)
template <int HASBN>
__global__ __launch_bounds__(256) void agg_pk_half(const float4* __restrict__ h4,
                                                   const int* __restrict__ off,
                                                   const int* __restrict__ eidx,
                                                   const float4* __restrict__ scale4,
                                                   const float4* __restrict__ shift4,
                                                   unsigned short* __restrict__ zp,
                                                   int jsel) {
  const int n = blockIdx.x * 4 + (threadIdx.x >> 6);
  if (n >= N_NODES) return;
  const int lane = threadIdx.x & 63;
  const int ROW = 128;
  const int cj = jsel * 64 + lane;
  float4 sc, sh;
  if (HASBN) {
    sc = scale4[cj];
    sh = shift4[cj];
  }
  const float4* hn = h4 + (long long)n * ROW;
  float4 a0 = hn[cj];
  float4 v = HASBN ? bnrelu4(a0, sc, sh) : a0;

  int p = off[n];
  const int pe = off[n + 1];
  for (; p < pe; p += 16) {
    const float4* hp[16];
    float m[16];
#pragma unroll
    for (int e = 0; e < 16; ++e) {
      bool ok = (p + e) < pe;
      int idx = ok ? (p + e) : (pe - 1);
      hp[e] = h4 + (long long)eidx[idx] * ROW;
      m[e] = ok ? 1.f : 0.f;
    }
    float4 t[16];
#pragma unroll
    for (int e = 0; e < 16; ++e) {
      t[e] = hp[e][cj];
      if (HASBN) t[e] = bnrelu4(t[e], sc, sh);
    }
#pragma unroll
    for (int e = 0; e < 16; ++e) {
      v.x = fmaf(t[e].x, m[e], v.x);
      v.y = fmaf(t[e].y, m[e], v.y);
      v.z = fmaf(t[e].z, m[e], v.z);
      v.w = fmaf(t[e].w, m[e], v.w);
    }
  }
  const int nd = n & 63, tile = n >> 6;
  const int ks = cj >> 3, k4 = cj & 7;
  size_t base = ((size_t)tile * 16 + ks) * 4096 + (size_t)nd * 32 + (size_t)k4 * 4;
  split4_store(v, zp + base, zp + base + 2048);
}

// ------------------------------------------------- W pre-pack: ALL weights in one launch.
__global__ __launch_bounds__(256) void wt_build_all(
    const float* __restrict__ w0a, const float* __restrict__ w0b,
    const float* __restrict__ w1a, const float* __restrict__ w1b,
    const float* __restrict__ w2a, const float* __restrict__ w2b,
    const float* __restrict__ wc1,
    unsigned short* __restrict__ p0a, unsigned short* __restrict__ p0b,
    unsigned short* __restrict__ p1a, unsigned short* __restrict__ p1b,
    unsigned short* __restrict__ p2a, unsigned short* __restrict__ p2b,
    unsigned short* __restrict__ pc1) {
  int gid = blockIdx.x * 256 + threadIdx.x;
  const float* W;
  unsigned short* Wp;
  int KS, lg;
  if (gid < 131072) {
    W = w0a; Wp = p0a; KS = 8; lg = gid;
  } else {
    int g2 = gid - 131072;
    int seg = g2 >> 18;
    lg = g2 & 262143;
    KS = 16;
    if (seg == 0) { W = w0b; Wp = p0b; }
    else if (seg == 1) { W = w1a; Wp = p1a; }
    else if (seg == 2) { W = w1b; Wp = p1b; }
    else if (seg == 3) { W = w2a; Wp = p2a; }
    else if (seg == 4) { W = w2b; Wp = p2b; }
    else if (seg == 5) { W = wc1; Wp = pc1; }
    else return;
  }
  int blk = lg >> 13;
  int rem = lg & 8191;
  int cf = rem >> 9;
  int q = (rem >> 7) & 3;
  int c = (rem >> 3) & 15;
  int j = rem & 7;
  int bx = blk / KS, ks = blk - bx * KS;
  int chan = bx * 256 + cf * 16 + c;
  int k = ks * 32 + q * 8 + j;
  float v = W[(size_t)k * 512 + chan];
  unsigned short h, l;
  split_bf16(v, h, l);
  Wp[(size_t)blk * 16384 + rem] = h;
  Wp[(size_t)blk * 16384 + 8192 + rem] = l;
}

// ------------------------------------------------- LDS-free split-bf16 MFMA GEMM on node-block A.
// Register K pipeline with LIVE-RANGE FENCE: empty inline asm pins next-stage operands in
// VGPRs after this stage's MFMAs, preventing the scheduler from folding loads into use sites
// (diagnosed: VGPR_Count=64 = acc only -> pipeline never materialized in prior rounds).
template <int KS, int STATS, int PACKOUT>
__global__ __launch_bounds__(256, 2) void gemm_pk(const unsigned short* __restrict__ Ap,
                                                  const unsigned short* __restrict__ Wp,
                                                  const float* __restrict__ bias,
                                                  float* __restrict__ Cf,
                                                  unsigned short* __restrict__ Cp,
                                                  float* __restrict__ stat_sum,
                                                  float* __restrict__ stat_sq,
                                                  int N, int NTtiles, int relu) {
  const int wg = blockIdx.x;
  const int bx = (wg >> 3) & 1;
  const int tile = (wg >> 4) * 8 + (wg & 7);
  if (tile >= NTtiles) return;
  const int tid = threadIdx.x;
  const int wv = tid >> 6, ln = tid & 63;
  const int n0 = tile * 64;
  const int q = ln >> 4, ccs = ln & 15;

  f32x4 acc[4][4];
#pragma unroll
  for (int i = 0; i < 4; ++i)
#pragma unroll
    for (int j = 0; j < 4; ++j) acc[i][j] = f32x4{0.f, 0.f, 0.f, 0.f};

  const unsigned short* wp =
      Wp + ((size_t)bx * KS) * 16384 + (size_t)(wv * 4) * 512 + (size_t)ln * 8;
  const unsigned short* ap =
      Ap + (size_t)tile * KS * 4096 + (size_t)ccs * 32 + (size_t)q * 8;

  bf16x8 wh[2][4], wl[2][4], ah[2][4], al[2][4];

#define LOADSTG(B, KSI)                                      \
  {                                                          \
    const unsigned short* w_ = wp + (size_t)(KSI) * 16384;   \
    const unsigned short* a_ = ap + (size_t)(KSI) * 4096;    \
    _Pragma("unroll") for (int i_ = 0; i_ < 4; ++i_) {       \
      wh[B][i_] = *(const bf16x8*)(w_ + i_ * 512);           \
      wl[B][i_] = *(const bf16x8*)(w_ + 8192 + i_ * 512);    \
      ah[B][i_] = *(const bf16x8*)(a_ + i_ * 512);           \
      al[B][i_] = *(const bf16x8*)(a_ + 2048 + i_ * 512);    \
    }                                                        \
  }

// pin buffer B's 16 operand vectors live (64 VGPRs) at this program point
#define KEEPLIVE(B)                                                           \
  asm volatile(""                                                             \
               : "+v"(wh[B][0]), "+v"(wh[B][1]), "+v"(wh[B][2]),              \
                 "+v"(wh[B][3]), "+v"(wl[B][0]), "+v"(wl[B][1]),              \
                 "+v"(wl[B][2]), "+v"(wl[B][3]), "+v"(ah[B][0]),              \
                 "+v"(ah[B][1]), "+v"(ah[B][2]), "+v"(ah[B][3]),              \
                 "+v"(al[B][0]), "+v"(al[B][1]), "+v"(al[B][2]),              \
                 "+v"(al[B][3]));

  LOADSTG(0, 0)
#pragma unroll
  for (int ks = 0; ks < KS; ++ks) {
    const int cur = ks & 1;
    if (ks + 1 < KS) LOADSTG(cur ^ 1, ks + 1)
#pragma unroll
    for (int i = 0; i < 4; ++i)
#pragma unroll
      for (int j = 0; j < 4; ++j) {
        acc[i][j] = __builtin_amdgcn_mfma_f32_16x16x32_bf16(wh[cur][i], ah[cur][j], acc[i][j], 0, 0, 0);
        acc[i][j] = __builtin_amdgcn_mfma_f32_16x16x32_bf16(wh[cur][i], al[cur][j], acc[i][j], 0, 0, 0);
        acc[i][j] = __builtin_amdgcn_mfma_f32_16x16x32_bf16(wl[cur][i], ah[cur][j], acc[i][j], 0, 0, 0);
      }
    if (ks + 1 < KS) KEEPLIVE(cur ^ 1)  // waitcnt for next stage lands AFTER this stage's MFMAs
  }
#undef LOADSTG
#undef KEEPLIVE

  // epilogue: acc row = chan ((ln>>4)*4+reg), col = node (ln&15)
  const int chanb = bx * 256 + wv * 64 + (ln >> 4) * 4;
  float4 s4[4], q4[4];
  if (STATS) {
#pragma unroll
    for (int i = 0; i < 4; ++i) {
      s4[i] = make_float4(0.f, 0.f, 0.f, 0.f);
      q4[i] = make_float4(0.f, 0.f, 0.f, 0.f);
    }
  }
#pragma unroll
  for (int j = 0; j < 4; ++j) {
    int node = n0 + j * 16 + (ln & 15);
    bool valid = node < N;
    int nd = node & 63;
    int tile2 = node >> 6;
#pragma unroll
    for (int i = 0; i < 4; ++i) {
      int chan = chanb + i * 16;
      float4 bv = *(const float4*)(bias + chan);
      f32x4 a = acc[i][j];
      float4 o;
      o.x = a[0] + bv.x;
      o.y = a[1] + bv.y;
      o.z = a[2] + bv.z;
      o.w = a[3] + bv.w;
      if (relu) {
        o.x = fmaxf(o.x, 0.f);
        o.y = fmaxf(o.y, 0.f);
        o.z = fmaxf(o.z, 0.f);
        o.w = fmaxf(o.w, 0.f);
      }
      if (PACKOUT) {
        if (valid) {
          size_t base = ((size_t)tile2 * 16 + (size_t)(chan >> 5)) * 4096 +
                        (size_t)nd * 32 + (size_t)(chan & 31);
          split4_store(o, Cp + base, Cp + base + 2048);
        }
      } else {
        if (valid) *(float4*)(Cf + (size_t)node * 512 + chan) = o;
        if (STATS) {
          if (!valid) o = make_float4(0.f, 0.f, 0.f, 0.f);
          s4[i].x += o.x; s4[i].y += o.y; s4[i].z += o.z; s4[i].w += o.w;
          q4[i].x += o.x * o.x; q4[i].y += o.y * o.y;
          q4[i].z += o.z * o.z; q4[i].w += o.w * o.w;
        }
      }
    }
  }
  if (STATS) {
#pragma unroll
    for (int i = 0; i < 4; ++i) {
#pragma unroll
      for (int mask = 1; mask < 16; mask <<= 1) {
        s4[i].x += __shfl_xor(s4[i].x, mask);
        s4[i].y += __shfl_xor(s4[i].y, mask);
        s4[i].z += __shfl_xor(s4[i].z, mask);
        s4[i].w += __shfl_xor(s4[i].w, mask);
        q4[i].x += __shfl_xor(q4[i].x, mask);
        q4[i].y += __shfl_xor(q4[i].y, mask);
        q4[i].z += __shfl_xor(q4[i].z, mask);
        q4[i].w += __shfl_xor(q4[i].w, mask);
      }
    }
    if ((ln & 15) == 0) {
#pragma unroll
      for (int i = 0; i < 4; ++i) {
        int chan = chanb + i * 16;
        atomicAdd(&stat_sum[chan + 0], s4[i].x);
        atomicAdd(&stat_sum[chan + 1], s4[i].y);
        atomicAdd(&stat_sum[chan + 2], s4[i].z);
        atomicAdd(&stat_sum[chan + 3], s4[i].w);
        atomicAdd(&stat_sq[chan + 0], q4[i].x);
        atomicAdd(&stat_sq[chan + 1], q4[i].y);
        atomicAdd(&stat_sq[chan + 2], q4[i].z);
        atomicAdd(&stat_sq[chan + 3], q4[i].w);
      }
    }
  }
}

// ------------------------------------------------- BN finalize
__global__ __launch_bounds__(512) void bn_finalize(const float* __restrict__ sum,
                                                   const float* __restrict__ sumsq,
                                                   const float* __restrict__ g,
                                                   const float* __restrict__ b,
                                                   float* __restrict__ scale,
                                                   float* __restrict__ shift) {
  const int c = threadIdx.x;
  const float invN = 1.0f / (float)N_NODES;
  float mu = sum[c] * invN;
  float var = sumsq[c] * invN - mu * mu;
  float sc = rsqrtf(var + BN_EPS) * g[c];
  scale[c] = sc;
  shift[c] = fmaf(-mu, sc, b[c]);
}

// ------------------------------------------------- segmented add pool + fused BN -> node-block pack
__global__ __launch_bounds__(128) void gpool_bn(const float4* __restrict__ z4,
                                                const int* __restrict__ gstart,
                                                const float4* __restrict__ scale4,
                                                const float4* __restrict__ shift4,
                                                unsigned short* __restrict__ gpp) {
  const int g = blockIdx.x;
  const int t = threadIdx.x;
  const int s = gstart[g], e = gstart[g + 1];
  const float4 sc = scale4[t], sh = shift4[t];
  float4 acc = make_float4(0.f, 0.f, 0.f, 0.f);
  for (int n = s; n < e; ++n) {
    float4 v = bnrelu4(z4[(size_t)n * 128 + t], sc, sh);
    acc.x += v.x;
    acc.y += v.y;
    acc.z += v.z;
    acc.w += v.w;
  }
  const int tile = g >> 6, nd = g & 63;
  const int ks = t >> 3, k4 = t & 7;
  size_t base = ((size_t)tile * 16 + ks) * 4096 + (size_t)nd * 32 + (size_t)k4 * 4;
  split4_store(acc, gpp + base, gpp + base + 2048);
}

// ------------------------------------------------- classifier tail
__global__ __launch_bounds__(64) void clf2_softmax(const float* __restrict__ hidden,
                                                   const float* __restrict__ w2,
                                                   const float* __restrict__ b2,
                                                   float* __restrict__ out) {
  const int g = blockIdx.x;
  const int lane = threadIdx.x;
  float acc[10];
#pragma unroll
  for (int j = 0; j < 10; ++j) acc[j] = 0.f;
  for (int k = lane; k < HID; k += 64) {
    float hv = hidden[(long long)g * HID + k];
#pragma unroll
    for (int j = 0; j < 10; ++j) acc[j] += hv * w2[k * 10 + j];
  }
#pragma unroll
  for (int j = 0; j < 10; ++j) {
    for (int o = 32; o > 0; o >>= 1) acc[j] += __shfl_down(acc[j], o);
  }
  if (lane == 0) {
    float lg[10], pb[10];
    float mx = -1e30f;
#pragma unroll
    for (int j = 0; j < 10; ++j) {
      lg[j] = acc[j] + b2[j];
      mx = fmaxf(mx, lg[j]);
    }
    float se = 0.f;
#pragma unroll
    for (int j = 0; j < 10; ++j) {
      pb[j] = __expf(lg[j] - mx);
      se += pb[j];
    }
    float inv = 1.f / se;
    int am = 0;
    float best = lg[0];
#pragma unroll
    for (int j = 1; j < 10; ++j) {
      if (lg[j] > best) { best = lg[j]; am = j; }
    }
#pragma unroll
    for (int j = 0; j < 10; ++j) out[g * 10 + j] = lg[j];
#pragma unroll
    for (int j = 0; j < 10; ++j) out[N_GRAPHS * 10 + g * 10 + j] = pb[j] * inv;
    out[2 * N_GRAPHS * 10 + g] = (float)am;
#pragma unroll
    for (int j = 0; j < 10; ++j)
      out[2 * N_GRAPHS * 10 + N_GRAPHS + g * 10 + j] = (j == am) ? 1.f : 0.f;
  }
}

// ----------------------------------------------------------------- launch
extern "C" void kernel_launch(void* const* d_in, const int* in_sizes, int n_in,
                              void* d_out, int out_size, void* d_ws, size_t ws_size,
                              hipStream_t stream) {
  const float* x = (const float*)d_in[0];
  const int* src = (const int*)d_in[1];
  const int* dstE = src + N_EDGES;
  const int* batch = (const int*)d_in[2];
  const float* w0a = (const float*)d_in[3];
  const float* b0a = (const float*)d_in[4];
  const float* w0b = (const float*)d_in[5];
  const float* b0b = (const float*)d_in[6];
  const float* w1a = (const float*)d_in[7];
  const float* b1a = (const float*)d_in[8];
  const float* w1b = (const float*)d_in[9];
  const float* b1b = (const float*)d_in[10];
  const float* w2a = (const float*)d_in[11];
  const float* b2a = (const float*)d_in[12];
  const float* w2b = (const float*)d_in[13];
  const float* b2b = (const float*)d_in[14];
  const float* bng[3] = {(const float*)d_in[15], (const float*)d_in[17], (const float*)d_in[19]};
  const float* bnb[3] = {(const float*)d_in[16], (const float*)d_in[18], (const float*)d_in[20]};
  const float* clf_w1 = (const float*)d_in[21];
  const float* clf_b1 = (const float*)d_in[22];
  const float* clf_w2 = (const float*)d_in[23];
  const float* clf_b2 = (const float*)d_in[24];
  float* out = (float*)d_out;

  // ---- workspace layout (~218 MB); deg + per-layer bn stats contiguous for one memset
  const long long BUF = 25624576LL;
  float* bufA = (float*)d_ws;
  float* bufB = bufA + BUF;
  float* scale = bufB + BUF;          // 512
  float* shift = scale + 512;         // 512
  unsigned short* gpPack = (unsigned short*)(shift + 512);  // 524288 ushorts
  float* hidden = (float*)(gpPack + 524288);                // 262144 floats
  unsigned short* wp0a = (unsigned short*)(hidden + 262144);
  unsigned short* wp0b = wp0a + 262144;
  unsigned short* wp1a = wp0b + 524288;
  unsigned short* wp1b = wp1a + 524288;
  unsigned short* wp2a = wp1b + 524288;
  unsigned short* wp2b = wp2a + 524288;
  unsigned short* wpc1 = wp2b + 524288;
  int* deg = (int*)(wpc1 + 524288);
  float* bnsum = (float*)(deg + N_NODES);
  float* bnsq = bnsum + 3 * 512;
  int* off = (int*)(bnsq + 3 * 512);
  int* cursor = off + N_NODES + 1;
  int* eidx = cursor + N_NODES;
  int* gstart = eidx + N_EDGES;

  hipMemsetAsync(deg, 0, (N_NODES + 6 * 512) * sizeof(int), stream);
  hipLaunchKernelGGL(hist_dst, dim3(3125), dim3(256), 0, stream, dstE, deg);
  hipLaunchKernelGGL(scan_deg, dim3(1), dim3(1024), 0, stream, deg, off, cursor, batch, gstart);
  hipLaunchKernelGGL(fill_csr, dim3(3125), dim3(256), 0, stream, src, dstE, cursor, eidx);
  hipLaunchKernelGGL(wt_build_all, dim3(6656), dim3(256), 0, stream,
                     w0a, w0b, w1a, w1b, w2a, w2b, clf_w1,
                     wp0a, wp0b, wp1a, wp1b, wp2a, wp2b, wpc1);

  const unsigned short* wpa[3] = {wp0a, wp1a, wp2a};
  const unsigned short* wpb[3] = {wp0b, wp1b, wp2b};
  const float* ba[3] = {b0a, b1a, b2a};
  const float* bb[3] = {b0b, b1b, b2b};

  const int NT = (N_NODES + 63) / 64;            // 782
  const int GB = ((NT + 7) / 8) * 16;            // 1568 (XCD-paired 1-D grid)
  const int nagg = (N_NODES + 3) / 4;

  float* P = bufA;
  float* Q = bufB;
  for (int layer = 0; layer < 3; ++layer) {
    if (layer == 0) {
      hipLaunchKernelGGL((agg_pk<1, 0>), dim3(nagg), dim3(256), 0, stream,
                         (const float4*)x, off, eidx, nullptr, nullptr,
                         (unsigned short*)Q);
    } else {
      hipLaunchKernelGGL((agg_pk_half<1>), dim3(nagg), dim3(256), 0, stream,
                         (const float4*)P, off, eidx, (const float4*)scale,
                         (const float4*)shift, (unsigned short*)Q, 0);
      hipLaunchKernelGGL((agg_pk_half<1>), dim3(nagg), dim3(256), 0, stream,
                         (const float4*)P, off, eidx, (const float4*)scale,
                         (const float4*)shift, (unsigned short*)Q, 1);
    }
    { float* t = P; P = Q; Q = t; }
    if (layer == 0) {
      hipLaunchKernelGGL((gemm_pk<8, 0, 1>), dim3(GB), dim3(256), 0, stream,
                         (const unsigned short*)P, wpa[layer], ba[layer],
                         (float*)nullptr, (unsigned short*)Q, nullptr, nullptr,
                         N_NODES, NT, 1);
    } else {
      hipLaunchKernelGGL((gemm_pk<16, 0, 1>), dim3(GB), dim3(256), 0, stream,
                         (const unsigned short*)P, wpa[layer], ba[layer],
                         (float*)nullptr, (unsigned short*)Q, nullptr, nullptr,
                         N_NODES, NT, 1);
    }
    { float* t = P; P = Q; Q = t; }
    hipLaunchKernelGGL((gemm_pk<16, 1, 0>), dim3(GB), dim3(256), 0, stream,
                       (const unsigned short*)P, wpb[layer], bb[layer],
                       Q, (unsigned short*)nullptr, bnsum + layer * 512, bnsq + layer * 512,
                       N_NODES, NT, 0);
    { float* t = P; P = Q; Q = t; }
    hipLaunchKernelGGL(bn_finalize, dim3(1), dim3(512), 0, stream,
                       bnsum + layer * 512, bnsq + layer * 512,
                       bng[layer], bnb[layer], scale, shift);
  }

  hipLaunchKernelGGL(gpool_bn, dim3(N_GRAPHS), dim3(128), 0, stream,
                     (const float4*)P, gstart, (const float4*)scale,
                     (const float4*)shift, gpPack);
  hipLaunchKernelGGL((gemm_pk<16, 0, 0>), dim3(16), dim3(256), 0, stream,
                     (const unsigned short*)gpPack, wpc1, clf_b1,
                     hidden, (unsigned short*)nullptr, nullptr, nullptr,
                     N_GRAPHS, 8, 1);
  hipLaunchKernelGGL(clf2_softmax, dim3(N_GRAPHS), dim3(64), 0, stream,
                     hidden, clf_w2, clf_b2, out);
}

// Round 21
// 1549.443 us; speedup vs baseline: 1.2072x; 1.0015x over previous
//
#include <hip/hip_runtime.h>

#define N_NODES 50000
#define N_EDGES 800000
#define N_GRAPHS 512
#define IN_DIM 256
#define HID 512
#define BN_EPS 1e-5f

typedef __attribute__((ext_vector_type(8))) short bf16x8;
typedef __attribute__((ext_vector_type(4))) float f32x4;

__device__ inline void split_bf16(float a, unsigned short& hi, unsigned short& lo) {
  unsigned u = __float_as_uint(a);
  hi = (unsigned short)(u >> 16);
  float fh = __uint_as_float(u & 0xFFFF0000u);
  float r = a - fh;
  lo = (unsigned short)(__float_as_uint(r) >> 16);
}

__device__ inline void split4_store(float4 v, unsigned short* hip, unsigned short* lop) {
  unsigned short h0, h1, h2, h3, l0, l1, l2, l3;
  split_bf16(v.x, h0, l0);
  split_bf16(v.y, h1, l1);
  split_bf16(v.z, h2, l2);
  split_bf16(v.w, h3, l3);
  uint2 hv, lv;
  hv.x = (unsigned)h0 | ((unsigned)h1 << 16);
  hv.y = (unsigned)h2 | ((unsigned)h3 << 16);
  lv.x = (unsigned)l0 | ((unsigned)l1 << 16);
  lv.y = (unsigned)l2 | ((unsigned)l3 << 16);
  *(uint2*)hip = hv;
  *(uint2*)lop = lv;
}

__device__ inline float4 bnrelu4(float4 v, float4 s, float4 h) {
  float4 o;
  o.x = fmaxf(fmaf(v.x, s.x, h.x), 0.f);
  o.y = fmaxf(fmaf(v.y, s.y, h.y), 0.f);
  o.z = fmaxf(fmaf(v.z, s.z, h.z), 0.f);
  o.w = fmaxf(fmaf(v.w, s.w, h.w), 0.f);
  return o;
}

// issue-pinned 16B load: volatile asm keeps issue order; NO implicit waitcnt —
// caller must s_waitcnt before consuming the result.
__device__ __forceinline__ bf16x8 gld16(const unsigned short* p) {
  bf16x8 r;
  asm volatile("global_load_dwordx4 %0, %1, off" : "=v"(r) : "v"(p));
  return r;
}

// ------------------------------------------------- CSR build
__global__ __launch_bounds__(256) void hist_dst(const int* __restrict__ dst,
                                                int* __restrict__ deg) {
  for (int e = blockIdx.x * 256 + threadIdx.x; e < N_EDGES; e += gridDim.x * 256)
    atomicAdd(&deg[dst[e]], 1);
}

// exclusive scan (single block) + pool bounds folded into idle lanes
__global__ __launch_bounds__(1024) void scan_deg(const int* __restrict__ deg,
                                                 int* __restrict__ off,
                                                 int* __restrict__ cursor,
                                                 const int* __restrict__ batch,
                                                 int* __restrict__ gstart) {
  __shared__ int partial[1024];
  const int t = threadIdx.x;
  if (t < 512) {
    int lo = 0, hi = N_NODES;
    while (lo < hi) {
      int mid = (lo + hi) >> 1;
      if (batch[mid] < t) lo = mid + 1;
      else hi = mid;
    }
    gstart[t] = lo;
    if (t == 0) gstart[N_GRAPHS] = N_NODES;
  }
  const int CHUNK = 49;
  const int base = t * CHUNK;
  int mysum = 0;
  for (int i = 0; i < CHUNK; ++i) {
    int idx = base + i;
    if (idx < N_NODES) mysum += deg[idx];
  }
  partial[t] = mysum;
  __syncthreads();
  for (int st = 1; st < 1024; st <<= 1) {
    int v = (t >= st) ? partial[t - st] : 0;
    __syncthreads();
    partial[t] += v;
    __syncthreads();
  }
  int run = partial[t] - mysum;
  for (int i = 0; i < CHUNK; ++i) {
    int idx = base + i;
    if (idx < N_NODES) {
      off[idx] = run;
      cursor[idx] = run;
      run += deg[idx];
    }
  }
  if (t == 1023) off[N_NODES] = N_EDGES;
}

__global__ __launch_bounds__(256) void fill_csr(const int* __restrict__ src,
                                                const int* __restrict__ dst,
                                                int* __restrict__ cursor,
                                                int* __restrict__ eidx) {
  for (int e = blockIdx.x * 256 + threadIdx.x; e < N_EDGES; e += gridDim.x * 256) {
    int p = atomicAdd(&cursor[dst[e]], 1);
    eidx[p] = src[e];
  }
}

// ------------------------------------------------- gather-aggregate -> node-block packed output
// Full-row version (layer 0, D=256). 16-deep edge unroll; clamped slots masked to 0.
template <int ROWF4, int HASBN>
__global__ __launch_bounds__(256) void agg_pk(const float4* __restrict__ h4,
                                              const int* __restrict__ off,
                                              const int* __restrict__ eidx,
                                              const float4* __restrict__ scale4,
                                              const float4* __restrict__ shift4,
                                              unsigned short* __restrict__ zp) {
  const int n = blockIdx.x * 4 + (threadIdx.x >> 6);
  if (n >= N_NODES) return;
  const int lane = threadIdx.x & 63;
  const int ROW = ROWF4 * 64;
  float4 sc[ROWF4], sh[ROWF4];
  if (HASBN) {
#pragma unroll
    for (int j = 0; j < ROWF4; ++j) {
      sc[j] = scale4[j * 64 + lane];
      sh[j] = shift4[j * 64 + lane];
    }
  }
  float4 v[ROWF4];
  const float4* hn = h4 + (long long)n * ROW;
#pragma unroll
  for (int j = 0; j < ROWF4; ++j) {
    float4 a = hn[j * 64 + lane];
    v[j] = HASBN ? bnrelu4(a, sc[j], sh[j]) : a;
  }

  int p = off[n];
  const int pe = off[n + 1];
  for (; p < pe; p += 16) {
    const float4* hp[16];
    float m[16];
#pragma unroll
    for (int e = 0; e < 16; ++e) {
      bool ok = (p + e) < pe;
      int idx = ok ? (p + e) : (pe - 1);
      hp[e] = h4 + (long long)eidx[idx] * ROW;
      m[e] = ok ? 1.f : 0.f;
    }
#pragma unroll
    for (int j = 0; j < ROWF4; ++j) {
      float4 t[16];
#pragma unroll
      for (int e = 0; e < 16; ++e) {
        t[e] = hp[e][j * 64 + lane];
        if (HASBN) t[e] = bnrelu4(t[e], sc[j], sh[j]);
      }
#pragma unroll
      for (int e = 0; e < 16; ++e) {
        v[j].x = fmaf(t[e].x, m[e], v[j].x);
        v[j].y = fmaf(t[e].y, m[e], v[j].y);
        v[j].z = fmaf(t[e].z, m[e], v[j].z);
        v[j].w = fmaf(t[e].w, m[e], v[j].w);
      }
    }
  }
  const int nd = n & 63, tile = n >> 6;
#pragma unroll
  for (int j = 0; j < ROWF4; ++j) {
    int cj = j * 64 + lane;
    int ks = cj >> 3, k4 = cj & 7;
    size_t base = ((size_t)tile * (ROWF4 * 8) + ks) * 4096 + (size_t)nd * 32 +
                  (size_t)k4 * 4;
    split4_store(v[j], zp + base, zp + base + 2048);
  }
}

// ------------------------------------------------- channel-half gather-aggregate (D=512)
template <int HASBN>
__global__ __launch_bounds__(256) void agg_pk_half(const float4* __restrict__ h4,
                                                   const int* __restrict__ off,
                                                   const int* __restrict__ eidx,
                                                   const float4* __restrict__ scale4,
                                                   const float4* __restrict__ shift4,
                                                   unsigned short* __restrict__ zp,
                                                   int jsel) {
  const int n = blockIdx.x * 4 + (threadIdx.x >> 6);
  if (n >= N_NODES) return;
  const int lane = threadIdx.x & 63;
  const int ROW = 128;
  const int cj = jsel * 64 + lane;
  float4 sc, sh;
  if (HASBN) {
    sc = scale4[cj];
    sh = shift4[cj];
  }
  const float4* hn = h4 + (long long)n * ROW;
  float4 a0 = hn[cj];
  float4 v = HASBN ? bnrelu4(a0, sc, sh) : a0;

  int p = off[n];
  const int pe = off[n + 1];
  for (; p < pe; p += 16) {
    const float4* hp[16];
    float m[16];
#pragma unroll
    for (int e = 0; e < 16; ++e) {
      bool ok = (p + e) < pe;
      int idx = ok ? (p + e) : (pe - 1);
      hp[e] = h4 + (long long)eidx[idx] * ROW;
      m[e] = ok ? 1.f : 0.f;
    }
    float4 t[16];
#pragma unroll
    for (int e = 0; e < 16; ++e) {
      t[e] = hp[e][cj];
      if (HASBN) t[e] = bnrelu4(t[e], sc, sh);
    }
#pragma unroll
    for (int e = 0; e < 16; ++e) {
      v.x = fmaf(t[e].x, m[e], v.x);
      v.y = fmaf(t[e].y, m[e], v.y);
      v.z = fmaf(t[e].z, m[e], v.z);
      v.w = fmaf(t[e].w, m[e], v.w);
    }
  }
  const int nd = n & 63, tile = n >> 6;
  const int ks = cj >> 3, k4 = cj & 7;
  size_t base = ((size_t)tile * 16 + ks) * 4096 + (size_t)nd * 32 + (size_t)k4 * 4;
  split4_store(v, zp + base, zp + base + 2048);
}

// ------------------------------------------------- W pre-pack: ALL weights in one launch.
__global__ __launch_bounds__(256) void wt_build_all(
    const float* __restrict__ w0a, const float* __restrict__ w0b,
    const float* __restrict__ w1a, const float* __restrict__ w1b,
    const float* __restrict__ w2a, const float* __restrict__ w2b,
    const float* __restrict__ wc1,
    unsigned short* __restrict__ p0a, unsigned short* __restrict__ p0b,
    unsigned short* __restrict__ p1a, unsigned short* __restrict__ p1b,
    unsigned short* __restrict__ p2a, unsigned short* __restrict__ p2b,
    unsigned short* __restrict__ pc1) {
  int gid = blockIdx.x * 256 + threadIdx.x;
  const float* W;
  unsigned short* Wp;
  int KS, lg;
  if (gid < 131072) {
    W = w0a; Wp = p0a; KS = 8; lg = gid;
  } else {
    int g2 = gid - 131072;
    int seg = g2 >> 18;
    lg = g2 & 262143;
    KS = 16;
    if (seg == 0) { W = w0b; Wp = p0b; }
    else if (seg == 1) { W = w1a; Wp = p1a; }
    else if (seg == 2) { W = w1b; Wp = p1b; }
    else if (seg == 3) { W = w2a; Wp = p2a; }
    else if (seg == 4) { W = w2b; Wp = p2b; }
    else if (seg == 5) { W = wc1; Wp = pc1; }
    else return;
  }
  int blk = lg >> 13;
  int rem = lg & 8191;
  int cf = rem >> 9;
  int q = (rem >> 7) & 3;
  int c = (rem >> 3) & 15;
  int j = rem & 7;
  int bx = blk / KS, ks = blk - bx * KS;
  int chan = bx * 256 + cf * 16 + c;
  int k = ks * 32 + q * 8 + j;
  float v = W[(size_t)k * 512 + chan];
  unsigned short h, l;
  split_bf16(v, h, l);
  Wp[(size_t)blk * 16384 + rem] = h;
  Wp[(size_t)blk * 16384 + 8192 + rem] = l;
}

// ------------------------------------------------- LDS-free split-bf16 MFMA GEMM on node-block A.
// TRUE software pipeline: operand loads are volatile-asm global_load (issue point pinned),
// counted s_waitcnt vmcnt(16) drains only the PREVIOUS stage's loads, sched_barrier(0)
// prevents MFMA hoisting above the wait (guide rule #18). Loads for stage k+1 fly during
// stage k's 48 MFMAs.
template <int KS, int STATS, int PACKOUT>
__global__ __launch_bounds__(256, 2) void gemm_pk(const unsigned short* __restrict__ Ap,
                                                  const unsigned short* __restrict__ Wp,
                                                  const float* __restrict__ bias,
                                                  float* __restrict__ Cf,
                                                  unsigned short* __restrict__ Cp,
                                                  float* __restrict__ stat_sum,
                                                  float* __restrict__ stat_sq,
                                                  int N, int NTtiles, int relu) {
  const int wg = blockIdx.x;
  const int bx = (wg >> 3) & 1;
  const int tile = (wg >> 4) * 8 + (wg & 7);
  if (tile >= NTtiles) return;
  const int tid = threadIdx.x;
  const int wv = tid >> 6, ln = tid & 63;
  const int n0 = tile * 64;
  const int q = ln >> 4, ccs = ln & 15;

  f32x4 acc[4][4];
#pragma unroll
  for (int i = 0; i < 4; ++i)
#pragma unroll
    for (int j = 0; j < 4; ++j) acc[i][j] = f32x4{0.f, 0.f, 0.f, 0.f};

  const unsigned short* wp =
      Wp + ((size_t)bx * KS) * 16384 + (size_t)(wv * 4) * 512 + (size_t)ln * 8;
  const unsigned short* ap =
      Ap + (size_t)tile * KS * 4096 + (size_t)ccs * 32 + (size_t)q * 8;

  bf16x8 wh[2][4], wl[2][4], ah[2][4], al[2][4];

#define LOADSTG(B, KSI)                                      \
  {                                                          \
    const unsigned short* w_ = wp + (size_t)(KSI) * 16384;   \
    const unsigned short* a_ = ap + (size_t)(KSI) * 4096;    \
    _Pragma("unroll") for (int i_ = 0; i_ < 4; ++i_) {       \
      wh[B][i_] = gld16(w_ + i_ * 512);                      \
      wl[B][i_] = gld16(w_ + 8192 + i_ * 512);               \
      ah[B][i_] = gld16(a_ + i_ * 512);                      \
      al[B][i_] = gld16(a_ + 2048 + i_ * 512);               \
    }                                                        \
  }

  LOADSTG(0, 0)
#pragma unroll
  for (int ks = 0; ks < KS; ++ks) {
    const int cur = ks & 1;
    if (ks + 1 < KS) {
      LOADSTG(cur ^ 1, ks + 1)
      asm volatile("s_waitcnt vmcnt(16)");  // drain ONLY stage-cur's 16 loads
    } else {
      asm volatile("s_waitcnt vmcnt(0)");
    }
    __builtin_amdgcn_sched_barrier(0);  // keep MFMAs below the wait
#pragma unroll
    for (int i = 0; i < 4; ++i)
#pragma unroll
      for (int j = 0; j < 4; ++j) {
        acc[i][j] = __builtin_amdgcn_mfma_f32_16x16x32_bf16(wh[cur][i], ah[cur][j], acc[i][j], 0, 0, 0);
        acc[i][j] = __builtin_amdgcn_mfma_f32_16x16x32_bf16(wh[cur][i], al[cur][j], acc[i][j], 0, 0, 0);
        acc[i][j] = __builtin_amdgcn_mfma_f32_16x16x32_bf16(wl[cur][i], ah[cur][j], acc[i][j], 0, 0, 0);
      }
  }
#undef LOADSTG

  // epilogue: acc row = chan ((ln>>4)*4+reg), col = node (ln&15)
  const int chanb = bx * 256 + wv * 64 + (ln >> 4) * 4;
  float4 s4[4], q4[4];
  if (STATS) {
#pragma unroll
    for (int i = 0; i < 4; ++i) {
      s4[i] = make_float4(0.f, 0.f, 0.f, 0.f);
      q4[i] = make_float4(0.f, 0.f, 0.f, 0.f);
    }
  }
#pragma unroll
  for (int j = 0; j < 4; ++j) {
    int node = n0 + j * 16 + (ln & 15);
    bool valid = node < N;
    int nd = node & 63;
    int tile2 = node >> 6;
#pragma unroll
    for (int i = 0; i < 4; ++i) {
      int chan = chanb + i * 16;
      float4 bv = *(const float4*)(bias + chan);
      f32x4 a = acc[i][j];
      float4 o;
      o.x = a[0] + bv.x;
      o.y = a[1] + bv.y;
      o.z = a[2] + bv.z;
      o.w = a[3] + bv.w;
      if (relu) {
        o.x = fmaxf(o.x, 0.f);
        o.y = fmaxf(o.y, 0.f);
        o.z = fmaxf(o.z, 0.f);
        o.w = fmaxf(o.w, 0.f);
      }
      if (PACKOUT) {
        if (valid) {
          size_t base = ((size_t)tile2 * 16 + (size_t)(chan >> 5)) * 4096 +
                        (size_t)nd * 32 + (size_t)(chan & 31);
          split4_store(o, Cp + base, Cp + base + 2048);
        }
      } else {
        if (valid) *(float4*)(Cf + (size_t)node * 512 + chan) = o;
        if (STATS) {
          if (!valid) o = make_float4(0.f, 0.f, 0.f, 0.f);
          s4[i].x += o.x; s4[i].y += o.y; s4[i].z += o.z; s4[i].w += o.w;
          q4[i].x += o.x * o.x; q4[i].y += o.y * o.y;
          q4[i].z += o.z * o.z; q4[i].w += o.w * o.w;
        }
      }
    }
  }
  if (STATS) {
#pragma unroll
    for (int i = 0; i < 4; ++i) {
#pragma unroll
      for (int mask = 1; mask < 16; mask <<= 1) {
        s4[i].x += __shfl_xor(s4[i].x, mask);
        s4[i].y += __shfl_xor(s4[i].y, mask);
        s4[i].z += __shfl_xor(s4[i].z, mask);
        s4[i].w += __shfl_xor(s4[i].w, mask);
        q4[i].x += __shfl_xor(q4[i].x, mask);
        q4[i].y += __shfl_xor(q4[i].y, mask);
        q4[i].z += __shfl_xor(q4[i].z, mask);
        q4[i].w += __shfl_xor(q4[i].w, mask);
      }
    }
    if ((ln & 15) == 0) {
#pragma unroll
      for (int i = 0; i < 4; ++i) {
        int chan = chanb + i * 16;
        atomicAdd(&stat_sum[chan + 0], s4[i].x);
        atomicAdd(&stat_sum[chan + 1], s4[i].y);
        atomicAdd(&stat_sum[chan + 2], s4[i].z);
        atomicAdd(&stat_sum[chan + 3], s4[i].w);
        atomicAdd(&stat_sq[chan + 0], q4[i].x);
        atomicAdd(&stat_sq[chan + 1], q4[i].y);
        atomicAdd(&stat_sq[chan + 2], q4[i].z);
        atomicAdd(&stat_sq[chan + 3], q4[i].w);
      }
    }
  }
}

// ------------------------------------------------- BN finalize
__global__ __launch_bounds__(512) void bn_finalize(const float* __restrict__ sum,
                                                   const float* __restrict__ sumsq,
                                                   const float* __restrict__ g,
                                                   const float* __restrict__ b,
                                                   float* __restrict__ scale,
                                                   float* __restrict__ shift) {
  const int c = threadIdx.x;
  const float invN = 1.0f / (float)N_NODES;
  float mu = sum[c] * invN;
  float var = sumsq[c] * invN - mu * mu;
  float sc = rsqrtf(var + BN_EPS) * g[c];
  scale[c] = sc;
  shift[c] = fmaf(-mu, sc, b[c]);
}

// ------------------------------------------------- segmented add pool + fused BN -> node-block pack
__global__ __launch_bounds__(128) void gpool_bn(const float4* __restrict__ z4,
                                                const int* __restrict__ gstart,
                                                const float4* __restrict__ scale4,
                                                const float4* __restrict__ shift4,
                                                unsigned short* __restrict__ gpp) {
  const int g = blockIdx.x;
  const int t = threadIdx.x;
  const int s = gstart[g], e = gstart[g + 1];
  const float4 sc = scale4[t], sh = shift4[t];
  float4 acc = make_float4(0.f, 0.f, 0.f, 0.f);
  for (int n = s; n < e; ++n) {
    float4 v = bnrelu4(z4[(size_t)n * 128 + t], sc, sh);
    acc.x += v.x;
    acc.y += v.y;
    acc.z += v.z;
    acc.w += v.w;
  }
  const int tile = g >> 6, nd = g & 63;
  const int ks = t >> 3, k4 = t & 7;
  size_t base = ((size_t)tile * 16 + ks) * 4096 + (size_t)nd * 32 + (size_t)k4 * 4;
  split4_store(acc, gpp + base, gpp + base + 2048);
}

// ------------------------------------------------- classifier tail
__global__ __launch_bounds__(64) void clf2_softmax(const float* __restrict__ hidden,
                                                   const float* __restrict__ w2,
                                                   const float* __restrict__ b2,
                                                   float* __restrict__ out) {
  const int g = blockIdx.x;
  const int lane = threadIdx.x;
  float acc[10];
#pragma unroll
  for (int j = 0; j < 10; ++j) acc[j] = 0.f;
  for (int k = lane; k < HID; k += 64) {
    float hv = hidden[(long long)g * HID + k];
#pragma unroll
    for (int j = 0; j < 10; ++j) acc[j] += hv * w2[k * 10 + j];
  }
#pragma unroll
  for (int j = 0; j < 10; ++j) {
    for (int o = 32; o > 0; o >>= 1) acc[j] += __shfl_down(acc[j], o);
  }
  if (lane == 0) {
    float lg[10], pb[10];
    float mx = -1e30f;
#pragma unroll
    for (int j = 0; j < 10; ++j) {
      lg[j] = acc[j] + b2[j];
      mx = fmaxf(mx, lg[j]);
    }
    float se = 0.f;
#pragma unroll
    for (int j = 0; j < 10; ++j) {
      pb[j] = __expf(lg[j] - mx);
      se += pb[j];
    }
    float inv = 1.f / se;
    int am = 0;
    float best = lg[0];
#pragma unroll
    for (int j = 1; j < 10; ++j) {
      if (lg[j] > best) { best = lg[j]; am = j; }
    }
#pragma unroll
    for (int j = 0; j < 10; ++j) out[g * 10 + j] = lg[j];
#pragma unroll
    for (int j = 0; j < 10; ++j) out[N_GRAPHS * 10 + g * 10 + j] = pb[j] * inv;
    out[2 * N_GRAPHS * 10 + g] = (float)am;
#pragma unroll
    for (int j = 0; j < 10; ++j)
      out[2 * N_GRAPHS * 10 + N_GRAPHS + g * 10 + j] = (j == am) ? 1.f : 0.f;
  }
}

// ----------------------------------------------------------------- launch
extern "C" void kernel_launch(void* const* d_in, const int* in_sizes, int n_in,
                              void* d_out, int out_size, void* d_ws, size_t ws_size,
                              hipStream_t stream) {
  const float* x = (const float*)d_in[0];
  const int* src = (const int*)d_in[1];
  const int* dstE = src + N_EDGES;
  const int* batch = (const int*)d_in[2];
  const float* w0a = (const float*)d_in[3];
  const float* b0a = (const float*)d_in[4];
  const float* w0b = (const float*)d_in[5];
  const float* b0b = (const float*)d_in[6];
  const float* w1a = (const float*)d_in[7];
  const float* b1a = (const float*)d_in[8];
  const float* w1b = (const float*)d_in[9];
  const float* b1b = (const float*)d_in[10];
  const float* w2a = (const float*)d_in[11];
  const float* b2a = (const float*)d_in[12];
  const float* w2b = (const float*)d_in[13];
  const float* b2b = (const float*)d_in[14];
  const float* bng[3] = {(const float*)d_in[15], (const float*)d_in[17], (const float*)d_in[19]};
  const float* bnb[3] = {(const float*)d_in[16], (const float*)d_in[18], (const float*)d_in[20]};
  const float* clf_w1 = (const float*)d_in[21];
  const float* clf_b1 = (const float*)d_in[22];
  const float* clf_w2 = (const float*)d_in[23];
  const float* clf_b2 = (const float*)d_in[24];
  float* out = (float*)d_out;

  // ---- workspace layout (~218 MB); deg + per-layer bn stats contiguous for one memset
  const long long BUF = 25624576LL;
  float* bufA = (float*)d_ws;
  float* bufB = bufA + BUF;
  float* scale = bufB + BUF;
  float* shift = scale + 512;
  unsigned short* gpPack = (unsigned short*)(shift + 512);
  float* hidden = (float*)(gpPack + 524288);
  unsigned short* wp0a = (unsigned short*)(hidden + 262144);
  unsigned short* wp0b = wp0a + 262144;
  unsigned short* wp1a = wp0b + 524288;
  unsigned short* wp1b = wp1a + 524288;
  unsigned short* wp2a = wp1b + 524288;
  unsigned short* wp2b = wp2a + 524288;
  unsigned short* wpc1 = wp2b + 524288;
  int* deg = (int*)(wpc1 + 524288);
  float* bnsum = (float*)(deg + N_NODES);
  float* bnsq = bnsum + 3 * 512;
  int* off = (int*)(bnsq + 3 * 512);
  int* cursor = off + N_NODES + 1;
  int* eidx = cursor + N_NODES;
  int* gstart = eidx + N_EDGES;

  hipMemsetAsync(deg, 0, (N_NODES + 6 * 512) * sizeof(int), stream);
  hipLaunchKernelGGL(hist_dst, dim3(3125), dim3(256), 0, stream, dstE, deg);
  hipLaunchKernelGGL(scan_deg, dim3(1), dim3(1024), 0, stream, deg, off, cursor, batch, gstart);
  hipLaunchKernelGGL(fill_csr, dim3(3125), dim3(256), 0, stream, src, dstE, cursor, eidx);
  hipLaunchKernelGGL(wt_build_all, dim3(6656), dim3(256), 0, stream,
                     w0a, w0b, w1a, w1b, w2a, w2b, clf_w1,
                     wp0a, wp0b, wp1a, wp1b, wp2a, wp2b, wpc1);

  const unsigned short* wpa[3] = {wp0a, wp1a, wp2a};
  const unsigned short* wpb[3] = {wp0b, wp1b, wp2b};
  const float* ba[3] = {b0a, b1a, b2a};
  const float* bb[3] = {b0b, b1b, b2b};

  const int NT = (N_NODES + 63) / 64;            // 782
  const int GB = ((NT + 7) / 8) * 16;            // 1568 (XCD-paired 1-D grid)
  const int nagg = (N_NODES + 3) / 4;

  float* P = bufA;
  float* Q = bufB;
  for (int layer = 0; layer < 3; ++layer) {
    if (layer == 0) {
      hipLaunchKernelGGL((agg_pk<1, 0>), dim3(nagg), dim3(256), 0, stream,
                         (const float4*)x, off, eidx, nullptr, nullptr,
                         (unsigned short*)Q);
    } else {
      hipLaunchKernelGGL((agg_pk_half<1>), dim3(nagg), dim3(256), 0, stream,
                         (const float4*)P, off, eidx, (const float4*)scale,
                         (const float4*)shift, (unsigned short*)Q, 0);
      hipLaunchKernelGGL((agg_pk_half<1>), dim3(nagg), dim3(256), 0, stream,
                         (const float4*)P, off, eidx, (const float4*)scale,
                         (const float4*)shift, (unsigned short*)Q, 1);
    }
    { float* t = P; P = Q; Q = t; }
    if (layer == 0) {
      hipLaunchKernelGGL((gemm_pk<8, 0, 1>), dim3(GB), dim3(256), 0, stream,
                         (const unsigned short*)P, wpa[layer], ba[layer],
                         (float*)nullptr, (unsigned short*)Q, nullptr, nullptr,
                         N_NODES, NT, 1);
    } else {
      hipLaunchKernelGGL((gemm_pk<16, 0, 1>), dim3(GB), dim3(256), 0, stream,
                         (const unsigned short*)P, wpa[layer], ba[layer],
                         (float*)nullptr, (unsigned short*)Q, nullptr, nullptr,
                         N_NODES, NT, 1);
    }
    { float* t = P; P = Q; Q = t; }
    hipLaunchKernelGGL((gemm_pk<16, 1, 0>), dim3(GB), dim3(256), 0, stream,
                       (const unsigned short*)P, wpb[layer], bb[layer],
                       Q, (unsigned short*)nullptr, bnsum + layer * 512, bnsq + layer * 512,
                       N_NODES, NT, 0);
    { float* t = P; P = Q; Q = t; }
    hipLaunchKernelGGL(bn_finalize, dim3(1), dim3(512), 0, stream,
                       bnsum + layer * 512, bnsq + layer * 512,
                       bng[layer], bnb[layer], scale, shift);
  }

  hipLaunchKernelGGL(gpool_bn, dim3(N_GRAPHS), dim3(128), 0, stream,
                     (const float4*)P, gstart, (const float4*)scale,
                     (const float4*)shift, gpPack);
  hipLaunchKernelGGL((gemm_pk<16, 0, 0>), dim3(16), dim3(256), 0, stream,
                     (const unsigned short*)gpPack, wpc1, clf_b1,
                     hidden, (unsigned short*)nullptr, nullptr, nullptr,
                     N_GRAPHS, 8, 1);
  hipLaunchKernelGGL(clf2_softmax, dim3(N_GRAPHS), dim3(64), 0, stream,
                     hidden, clf_w2, clf_b2, out);
}